// Round 1
// baseline (820.420 us; speedup 1.0000x reference)
//
#include <hip/hip_runtime.h>
#include <hip/hip_bf16.h>
#include <cfloat>

#define NNODE 4096
#define NEGV  -9000000000000000.0f

__device__ __forceinline__ float leaky(float x) { return x > 0.0f ? x : 0.2f * x; }

// ---------------------------------------------------------------------------
// GEMM: C[h] = A @ B[h].  A: MxK (row-major, stride K), B[h]: KxN (row-major,
// stride Nfull), C[h]: MxN (stride Nfull). 64x64 tile, 256 thr, 4x4 micro.
// grid = (M/64, Nfull/64, heads)
// ---------------------------------------------------------------------------
__global__ __launch_bounds__(256) void gemm64(
    const float* __restrict__ A, const float* __restrict__ B, float* __restrict__ C,
    int M, int K, int Nfull) {
  __shared__ float Ast[64][68];  // [k][row]  (transposed A tile)
  __shared__ float Bs[64][68];   // [k][col]
  const int t  = threadIdx.x;
  const int i0 = blockIdx.x * 64;
  const int c0 = blockIdx.y * 64;
  const int h  = blockIdx.z;
  const float* Bh = B + (size_t)h * K * Nfull;
  float*       Ch = C + (size_t)h * M * Nfull;
  const int tx = t & 15, ty = t >> 4;
  const int lrow = t >> 4;         // 0..15
  const int lcol = (t & 15) * 4;   // 0..60
  float acc[4][4] = {};

  for (int k0 = 0; k0 < K; k0 += 64) {
    #pragma unroll
    for (int s = 0; s < 4; ++s) {
      int r = lrow + s * 16;
      float4 av = *(const float4*)&A[(size_t)(i0 + r) * K + k0 + lcol];
      Ast[lcol + 0][r] = av.x;
      Ast[lcol + 1][r] = av.y;
      Ast[lcol + 2][r] = av.z;
      Ast[lcol + 3][r] = av.w;
      float4 bv = *(const float4*)&Bh[(size_t)(k0 + r) * Nfull + c0 + lcol];
      *(float4*)&Bs[r][lcol] = bv;
    }
    __syncthreads();
    #pragma unroll 8
    for (int k = 0; k < 64; ++k) {
      float4 a4 = *(const float4*)&Ast[k][ty * 4];
      float4 b4 = *(const float4*)&Bs[k][tx * 4];
      acc[0][0] += a4.x * b4.x; acc[0][1] += a4.x * b4.y; acc[0][2] += a4.x * b4.z; acc[0][3] += a4.x * b4.w;
      acc[1][0] += a4.y * b4.x; acc[1][1] += a4.y * b4.y; acc[1][2] += a4.y * b4.z; acc[1][3] += a4.y * b4.w;
      acc[2][0] += a4.z * b4.x; acc[2][1] += a4.z * b4.y; acc[2][2] += a4.z * b4.z; acc[2][3] += a4.z * b4.w;
      acc[3][0] += a4.w * b4.x; acc[3][1] += a4.w * b4.y; acc[3][2] += a4.w * b4.z; acc[3][3] += a4.w * b4.w;
    }
    __syncthreads();
  }
  #pragma unroll
  for (int mi = 0; mi < 4; ++mi) {
    #pragma unroll
    for (int ni = 0; ni < 4; ++ni)
      Ch[(size_t)(i0 + ty * 4 + mi) * Nfull + c0 + tx * 4 + ni] = acc[mi][ni];
  }
}

// ---------------------------------------------------------------------------
// fi[h][n] = h[h][n][:] . a1[h],  fj[h][n] = h[h][n][:] . a2[h]
// one wave per (h, n); avec layout: [h][2*F] (a1 then a2)
// ---------------------------------------------------------------------------
template<int F>
__global__ __launch_bounds__(256) void fifj_kernel(
    const float* __restrict__ hbuf, const float* __restrict__ avec,
    float* __restrict__ fi, float* __restrict__ fj) {
  const int gid  = blockIdx.x * 4 + (threadIdx.x >> 6);
  const int lane = threadIdx.x & 63;
  const int h = gid >> 12;       // / 4096
  const int n = gid & 4095;
  const float* hrow = hbuf + ((size_t)h * NNODE + n) * F;
  const float* a1 = avec + h * 2 * F;
  const float* a2 = a1 + F;
  float v1 = 0.f, v2 = 0.f;
  #pragma unroll
  for (int e = lane; e < F; e += 64) {
    float xv = hrow[e];
    v1 += xv * a1[e];
    v2 += xv * a2[e];
  }
  #pragma unroll
  for (int off = 32; off; off >>= 1) {
    v1 += __shfl_xor(v1, off);
    v2 += __shfl_xor(v2, off);
  }
  if (lane == 0) {
    fi[h * NNODE + n] = v1;
    fj[h * NNODE + n] = v2;
  }
}

// ---------------------------------------------------------------------------
// Per-row softmax stats for all NH heads at once (reads adj row once/pass):
//   m[h][i] = max_j s_hij  (== leaky(fi+max_nbr fj), or NEG if row empty)
//   l[h][i] = sum_j exp(s_hij - m)   (== NNODE if row empty: uniform case)
// grid = (NNODE), 256 threads
// ---------------------------------------------------------------------------
template<int NH>
__global__ __launch_bounds__(256) void ml_kernel(
    const int* __restrict__ adj, const float* __restrict__ fi,
    const float* __restrict__ fj, float* __restrict__ m_out, float* __restrict__ l_out) {
  const int i = blockIdx.x;
  const int t = threadIdx.x;
  const int* arow = adj + (size_t)i * NNODE;
  __shared__ float red[NH][4];
  __shared__ float bm[NH];
  float fih[NH];
  #pragma unroll
  for (int h = 0; h < NH; ++h) fih[h] = fi[h * NNODE + i];

  float mx[NH];
  #pragma unroll
  for (int h = 0; h < NH; ++h) mx[h] = -FLT_MAX;
  for (int j = t; j < NNODE; j += 256) {
    if (arow[j]) {
      #pragma unroll
      for (int h = 0; h < NH; ++h) mx[h] = fmaxf(mx[h], fj[h * NNODE + j]);
    }
  }
  const int lane = t & 63, w = t >> 6;
  #pragma unroll
  for (int h = 0; h < NH; ++h) {
    float v = mx[h];
    #pragma unroll
    for (int off = 32; off; off >>= 1) v = fmaxf(v, __shfl_xor(v, off));
    if (lane == 0) red[h][w] = v;
  }
  __syncthreads();
  if (t < NH) {
    float v = fmaxf(fmaxf(red[t][0], red[t][1]), fmaxf(red[t][2], red[t][3]));
    float fiv = fi[t * NNODE + i];
    float mm = (v > -3.0e38f) ? leaky(fiv + v) : NEGV;   // empty row -> NEG
    bm[t] = mm;
    m_out[t * NNODE + i] = mm;
  }
  __syncthreads();
  float bmr[NH];
  #pragma unroll
  for (int h = 0; h < NH; ++h) bmr[h] = bm[h];

  float sm[NH];
  #pragma unroll
  for (int h = 0; h < NH; ++h) sm[h] = 0.f;
  for (int j = t; j < NNODE; j += 256) {
    if (arow[j]) {
      #pragma unroll
      for (int h = 0; h < NH; ++h)
        sm[h] += __expf(leaky(fih[h] + fj[h * NNODE + j]) - bmr[h]);
    }
  }
  #pragma unroll
  for (int h = 0; h < NH; ++h) {
    float v = sm[h];
    #pragma unroll
    for (int off = 32; off; off >>= 1) v += __shfl_xor(v, off);
    if (lane == 0) red[h][w] = v;
  }
  __syncthreads();
  if (t < NH) {
    float v = red[t][0] + red[t][1] + red[t][2] + red[t][3];
    if (bm[t] < -8.0e15f) v = (float)NNODE;              // empty row: uniform
    l_out[t * NNODE + i] = v;
  }
}

// ---------------------------------------------------------------------------
// PV: out[i][o] = (1/l_i) * sum_j p_ij * h[j][o],
//   p_ij = adj ? exp(leaky(fi_i+fj_j) - m_i) : 0   (uniform 1.0 if row empty)
// 64-row x 64-col tile per block, j-tiles of 64, p & h staged in LDS,
// 4x4 micro-tile (2x ds_read_b128 + 16 fma per j).
// grid = (NNODE/64, F/64, heads)
// ---------------------------------------------------------------------------
template<int F>
__global__ __launch_bounds__(256) void pv_kernel(
    const float* __restrict__ hbuf, const float* __restrict__ fi,
    const float* __restrict__ fj, const float* __restrict__ m,
    const float* __restrict__ l, const int* __restrict__ adj,
    float* __restrict__ out, int out_stride) {
  __shared__ float pT[64][68];   // [j][row]
  __shared__ float ht[64][68];   // [j][o]
  __shared__ float fjL[64];
  __shared__ float fiL[64], mL[64], lL[64];
  const int t  = threadIdx.x;
  const int i0 = blockIdx.x * 64;
  const int ot = blockIdx.y;
  const int h  = blockIdx.z;
  const int hN = h * NNODE;
  const float* Hb = hbuf + (size_t)h * NNODE * F + ot * 64;
  const int ocol0 = h * F + ot * 64;

  if (t < 64) {
    fiL[t] = fi[hN + i0 + t];
    mL[t]  = m[hN + i0 + t];
    lL[t]  = l[hN + i0 + t];
  }
  __syncthreads();

  const int tx = t & 15, ty = t >> 4;
  const int ar = t >> 2;          // 0..63: row within tile (phase A)
  const int jc = (t & 3) * 16;    // j-chunk base (phase A)
  float acc[4][4] = {};

  for (int j0 = 0; j0 < NNODE; j0 += 64) {
    if (t < 64) fjL[t] = fj[hN + j0 + t];
    #pragma unroll
    for (int s = 0; s < 4; ++s) {
      int jr = (t >> 4) + s * 16;
      float4 hv = *(const float4*)&Hb[(size_t)(j0 + jr) * F + (t & 15) * 4];
      *(float4*)&ht[jr][(t & 15) * 4] = hv;
    }
    __syncthreads();   // S1: fjL/ht ready

    // phase A: compute p tile (transposed)
    {
      const float fir = fiL[ar];
      const float mr  = mL[ar];
      const bool uni  = (mr < -8.0e15f);
      const int* arowp = adj + (size_t)(i0 + ar) * NNODE + j0 + jc;
      #pragma unroll
      for (int g = 0; g < 4; ++g) {
        int4 av = *(const int4*)&arowp[g * 4];
        int jb = jc + g * 4;
        float s0 = leaky(fir + fjL[jb + 0]);
        float s1 = leaky(fir + fjL[jb + 1]);
        float s2 = leaky(fir + fjL[jb + 2]);
        float s3 = leaky(fir + fjL[jb + 3]);
        pT[jb + 0][ar] = uni ? 1.0f : (av.x ? __expf(s0 - mr) : 0.0f);
        pT[jb + 1][ar] = uni ? 1.0f : (av.y ? __expf(s1 - mr) : 0.0f);
        pT[jb + 2][ar] = uni ? 1.0f : (av.z ? __expf(s2 - mr) : 0.0f);
        pT[jb + 3][ar] = uni ? 1.0f : (av.w ? __expf(s3 - mr) : 0.0f);
      }
    }
    __syncthreads();   // S2: pT ready

    // phase B: accumulate 4x4 micro-tiles
    #pragma unroll 8
    for (int j = 0; j < 64; ++j) {
      float4 p4 = *(const float4*)&pT[j][ty * 4];
      float4 h4 = *(const float4*)&ht[j][tx * 4];
      acc[0][0] += p4.x * h4.x; acc[0][1] += p4.x * h4.y; acc[0][2] += p4.x * h4.z; acc[0][3] += p4.x * h4.w;
      acc[1][0] += p4.y * h4.x; acc[1][1] += p4.y * h4.y; acc[1][2] += p4.y * h4.z; acc[1][3] += p4.y * h4.w;
      acc[2][0] += p4.z * h4.x; acc[2][1] += p4.z * h4.y; acc[2][2] += p4.z * h4.z; acc[2][3] += p4.z * h4.w;
      acc[3][0] += p4.w * h4.x; acc[3][1] += p4.w * h4.y; acc[3][2] += p4.w * h4.z; acc[3][3] += p4.w * h4.w;
    }
    __syncthreads();   // S3: reads done before next iter's writes
  }

  #pragma unroll
  for (int mi = 0; mi < 4; ++mi) {
    int ri = ty * 4 + mi;
    float invl = 1.0f / lL[ri];
    #pragma unroll
    for (int ni = 0; ni < 4; ++ni)
      out[(size_t)(i0 + ri) * out_stride + ocol0 + tx * 4 + ni] = acc[mi][ni] * invl;
  }
}

// ---------------------------------------------------------------------------
// elu + log_softmax over 128 classes; one block (128 thr) per row
// ---------------------------------------------------------------------------
__global__ __launch_bounds__(128) void finalize_kernel(
    const float* __restrict__ out2, float* __restrict__ dout) {
  const int i = blockIdx.x, t = threadIdx.x;
  float v = out2[(size_t)i * 128 + t];
  float e = v > 0.f ? v : (__expf(v) - 1.0f);
  float mx = e;
  #pragma unroll
  for (int off = 32; off; off >>= 1) mx = fmaxf(mx, __shfl_xor(mx, off));
  __shared__ float r2[2];
  if ((t & 63) == 0) r2[t >> 6] = mx;
  __syncthreads();
  mx = fmaxf(r2[0], r2[1]);
  float s = __expf(e - mx);
  #pragma unroll
  for (int off = 32; off; off >>= 1) s += __shfl_xor(s, off);
  __shared__ float s2[2];
  if ((t & 63) == 0) s2[t >> 6] = s;
  __syncthreads();
  float sum = s2[0] + s2[1];
  dout[(size_t)i * 128 + t] = e - mx - __logf(sum);
}

// ---------------------------------------------------------------------------
extern "C" void kernel_launch(void* const* d_in, const int* in_sizes, int n_in,
                              void* d_out, int out_size, void* d_ws, size_t ws_size,
                              hipStream_t stream) {
  const float* x     = (const float*)d_in[0];
  const int*   adj   = (const int*)d_in[1];
  const float* W     = (const float*)d_in[2];
  const float* a     = (const float*)d_in[3];
  const float* W_out = (const float*)d_in[4];
  const float* a_out = (const float*)d_in[5];
  float* out = (float*)d_out;

  float* ws   = (float*)d_ws;
  float* h1   = ws;                       // 8*4096*64 = 2097152
  float* xcat = h1 + 8 * 4096 * 64;       // 4096*512  = 2097152
  float* h2   = xcat + 4096 * 512;        // 4096*128  = 524288
  float* out2 = h2 + 4096 * 128;          // 4096*128  = 524288
  float* fi1  = out2 + 4096 * 128;        // 32768
  float* fj1  = fi1 + 8 * 4096;
  float* m1   = fj1 + 8 * 4096;
  float* l1   = m1 + 8 * 4096;
  float* fi2  = l1 + 8 * 4096;            // 4096 each
  float* fj2  = fi2 + 4096;
  float* m2   = fj2 + 4096;
  float* l2   = m2 + 4096;

  // ---- layer 1 ----
  gemm64<<<dim3(64, 1, 8), 256, 0, stream>>>(x, W, h1, 4096, 512, 64);
  fifj_kernel<64><<<dim3(8 * 4096 / 4), 256, 0, stream>>>(h1, a, fi1, fj1);
  ml_kernel<8><<<dim3(4096), 256, 0, stream>>>(adj, fi1, fj1, m1, l1);
  pv_kernel<64><<<dim3(64, 1, 8), 256, 0, stream>>>(h1, fi1, fj1, m1, l1, adj, xcat, 512);

  // ---- layer 2 ----
  gemm64<<<dim3(64, 2, 1), 256, 0, stream>>>(xcat, W_out, h2, 4096, 512, 128);
  fifj_kernel<128><<<dim3(4096 / 4), 256, 0, stream>>>(h2, a_out, fi2, fj2);
  ml_kernel<1><<<dim3(4096), 256, 0, stream>>>(adj, fi2, fj2, m2, l2);
  pv_kernel<128><<<dim3(64, 2, 1), 256, 0, stream>>>(h2, fi2, fj2, m2, l2, adj, out2, 128);

  // ---- elu + log_softmax ----
  finalize_kernel<<<dim3(4096), 128, 0, stream>>>(out2, out);
}

// Round 2
// 474.136 us; speedup vs baseline: 1.7303x; 1.7303x over previous
//
#include <hip/hip_runtime.h>
#include <hip/hip_bf16.h>

#define NNODE 4096

typedef __attribute__((ext_vector_type(8))) short bf16x8;
typedef __attribute__((ext_vector_type(4))) float f32x4;
typedef __attribute__((ext_vector_type(4))) unsigned short us4;
typedef __attribute__((ext_vector_type(8))) unsigned short us8;

__device__ __forceinline__ float leaky(float x) { return x > 0.0f ? x : 0.2f * x; }

__device__ __forceinline__ unsigned short f2bf(float x) {
  __hip_bfloat16 b = __float2bfloat16(x);
  return __builtin_bit_cast(unsigned short, b);
}
__device__ __forceinline__ float bf2f(unsigned short u) {
  unsigned int v = ((unsigned int)u) << 16;
  return __builtin_bit_cast(float, v);
}

// ---------------------------------------------------------------------------
// GEMM: C[h] = A @ B[h].  A: MxK (row-major, stride K), B[h]: KxN (row-major,
// stride Nfull), C[h]: MxN (stride Nfull). fp32, 64x64 tile, 4x4 micro.
// grid = (M/64, Nfull/64, heads)
// ---------------------------------------------------------------------------
__global__ __launch_bounds__(256) void gemm64(
    const float* __restrict__ A, const float* __restrict__ B, float* __restrict__ C,
    int M, int K, int Nfull) {
  __shared__ float Ast[64][68];  // [k][row]
  __shared__ float Bs[64][68];   // [k][col]
  const int t  = threadIdx.x;
  const int i0 = blockIdx.x * 64;
  const int c0 = blockIdx.y * 64;
  const int h  = blockIdx.z;
  const float* Bh = B + (size_t)h * K * Nfull;
  float*       Ch = C + (size_t)h * M * Nfull;
  const int tx = t & 15, ty = t >> 4;
  const int lrow = t >> 4;
  const int lcol = (t & 15) * 4;
  float acc[4][4] = {};

  for (int k0 = 0; k0 < K; k0 += 64) {
    #pragma unroll
    for (int s = 0; s < 4; ++s) {
      int r = lrow + s * 16;
      float4 av = *(const float4*)&A[(size_t)(i0 + r) * K + k0 + lcol];
      Ast[lcol + 0][r] = av.x;
      Ast[lcol + 1][r] = av.y;
      Ast[lcol + 2][r] = av.z;
      Ast[lcol + 3][r] = av.w;
      float4 bv = *(const float4*)&Bh[(size_t)(k0 + r) * Nfull + c0 + lcol];
      *(float4*)&Bs[r][lcol] = bv;
    }
    __syncthreads();
    #pragma unroll 8
    for (int k = 0; k < 64; ++k) {
      float4 a4 = *(const float4*)&Ast[k][ty * 4];
      float4 b4 = *(const float4*)&Bs[k][tx * 4];
      acc[0][0] += a4.x * b4.x; acc[0][1] += a4.x * b4.y; acc[0][2] += a4.x * b4.z; acc[0][3] += a4.x * b4.w;
      acc[1][0] += a4.y * b4.x; acc[1][1] += a4.y * b4.y; acc[1][2] += a4.y * b4.z; acc[1][3] += a4.y * b4.w;
      acc[2][0] += a4.z * b4.x; acc[2][1] += a4.z * b4.y; acc[2][2] += a4.z * b4.z; acc[2][3] += a4.z * b4.w;
      acc[3][0] += a4.w * b4.x; acc[3][1] += a4.w * b4.y; acc[3][2] += a4.w * b4.z; acc[3][3] += a4.w * b4.w;
    }
    __syncthreads();
  }
  #pragma unroll
  for (int mi = 0; mi < 4; ++mi) {
    #pragma unroll
    for (int ni = 0; ni < 4; ++ni)
      Ch[(size_t)(i0 + ty * 4 + mi) * Nfull + c0 + tx * 4 + ni] = acc[mi][ni];
  }
}

// ---------------------------------------------------------------------------
// transpose + bf16 cast: src [h][n][Fsrc] f32 -> dst [h][Fsrc][n] bf16
// grid = (N/64, Fsrc/64, heads)
// ---------------------------------------------------------------------------
__global__ __launch_bounds__(256) void transpose_bf16(
    const float* __restrict__ src, short* __restrict__ dst, int Fsrc) {
  __shared__ float tile[64][68];
  const int t  = threadIdx.x;
  const int n0 = blockIdx.x * 64, o0 = blockIdx.y * 64;
  const int h  = blockIdx.z;
  const float* S = src + ((size_t)h * NNODE + n0) * Fsrc + o0;
  short* D = dst + ((size_t)h * Fsrc + o0) * NNODE + n0;
  const int r = t >> 2, cs = (t & 3) * 16;
  #pragma unroll
  for (int k2 = 0; k2 < 4; ++k2) {
    float4 v = *(const float4*)&S[(size_t)r * Fsrc + cs + k2 * 4];
    *(float4*)&tile[r][cs + k2 * 4] = v;
  }
  __syncthreads();
  const int o = t >> 2, ns = (t & 3) * 16;
  us8 u0, u1;
  #pragma unroll
  for (int e = 0; e < 8; ++e) u0[e] = f2bf(tile[ns + e][o]);
  #pragma unroll
  for (int e = 0; e < 8; ++e) u1[e] = f2bf(tile[ns + 8 + e][o]);
  *(us8*)&D[(size_t)o * NNODE + ns]     = u0;
  *(us8*)&D[(size_t)o * NNODE + ns + 8] = u1;
}

// ---------------------------------------------------------------------------
// fi[h][n] = h[h][n][:] . a1[h],  fj[h][n] = h[h][n][:] . a2[h]
// one wave per (h, n); avec layout: [h][2*F] (a1 then a2)
// ---------------------------------------------------------------------------
template<int F>
__global__ __launch_bounds__(256) void fifj_kernel(
    const float* __restrict__ hbuf, const float* __restrict__ avec,
    float* __restrict__ fi, float* __restrict__ fj) {
  const int gid  = blockIdx.x * 4 + (threadIdx.x >> 6);
  const int lane = threadIdx.x & 63;
  const int h = gid >> 12;
  const int n = gid & 4095;
  const float* hrow = hbuf + ((size_t)h * NNODE + n) * F;
  const float* a1 = avec + h * 2 * F;
  const float* a2 = a1 + F;
  float v1 = 0.f, v2 = 0.f;
  #pragma unroll
  for (int e = lane; e < F; e += 64) {
    float xv = hrow[e];
    v1 += xv * a1[e];
    v2 += xv * a2[e];
  }
  #pragma unroll
  for (int off = 32; off; off >>= 1) {
    v1 += __shfl_xor(v1, off);
    v2 += __shfl_xor(v2, off);
  }
  if (lane == 0) {
    fi[h * NNODE + n] = v1;
    fj[h * NNODE + n] = v2;
  }
}

// ---------------------------------------------------------------------------
// PV with MFMA (bf16):
//   p_ij = adj ? exp(leaky(fi_i + fj_j)) : 0      (no max-subtraction: fp32-safe)
//   out[i][o] = (sum_j p_ij * h[j][o]) / (sum_j p_ij)
// block: 64 i-rows x 64 o-cols, 4 waves in 2x2; per wave 2x2 frags of 16x16.
// hT: [head][Fh][NNODE] bf16 (Fh = gridDim.y*64). grid = (NNODE/64, Fh/64, NH)
// ---------------------------------------------------------------------------
__global__ __launch_bounds__(256) void pv_mfma(
    const short* __restrict__ hT, const float* __restrict__ fi,
    const float* __restrict__ fj, const int* __restrict__ adj,
    float* __restrict__ out, int out_stride) {
  __shared__ short pT[64][72];    // [i-row][j] bf16, stride 144B
  __shared__ short hTl[64][72];   // [o-col][j] bf16
  __shared__ float fjL[64];
  __shared__ float lred[64][4];
  __shared__ float invl[64];

  const int t    = threadIdx.x;
  const int lane = t & 63;
  const int w    = t >> 6;
  const int i0   = blockIdx.x * 64;
  const int ot   = blockIdx.y;
  const int h    = blockIdx.z;
  const int Fh   = gridDim.y * 64;
  const int hN   = h * NNODE;
  const short* hTs = hT + ((size_t)h * Fh + ot * 64) * NNODE;
  const int ocol0 = h * Fh + ot * 64;

  const int R0 = (w >> 1) * 32;   // wave row base
  const int C0 = (w & 1) * 32;    // wave col base
  const int lr = lane & 15;
  const int lk = lane >> 4;

  const int ar = t >> 2;          // phase-A row 0..63
  const int jc = (t & 3) * 16;    // phase-A j chunk
  const float fir = fi[hN + i0 + ar];

  f32x4 acc[2][2] = {};
  float lsum = 0.0f;

  for (int j0 = 0; j0 < NNODE; j0 += 64) {
    // stage hT tile (64 o x 64 j)
    {
      const int o = t >> 2, seg = t & 3;
      const short* src = hTs + (size_t)o * NNODE + j0 + seg * 16;
      float4 v0 = *(const float4*)(src);
      float4 v1 = *(const float4*)(src + 8);
      *(float4*)&hTl[o][seg * 16]     = v0;
      *(float4*)&hTl[o][seg * 16 + 8] = v1;
    }
    if (t < 64) fjL[t] = fj[hN + j0 + t];
    __syncthreads();  // S1

    // phase A: compute p tile into pT (bf16)
    {
      const int* arowp = adj + (size_t)(i0 + ar) * NNODE + j0 + jc;
      #pragma unroll
      for (int g = 0; g < 4; ++g) {
        int4 av = *(const int4*)&arowp[g * 4];
        int jb = jc + g * 4;
        float p0 = av.x ? __expf(leaky(fir + fjL[jb + 0])) : 0.0f;
        float p1 = av.y ? __expf(leaky(fir + fjL[jb + 1])) : 0.0f;
        float p2 = av.z ? __expf(leaky(fir + fjL[jb + 2])) : 0.0f;
        float p3 = av.w ? __expf(leaky(fir + fjL[jb + 3])) : 0.0f;
        us4 pk;
        pk[0] = f2bf(p0); pk[1] = f2bf(p1); pk[2] = f2bf(p2); pk[3] = f2bf(p3);
        // accumulate the ROUNDED p so the normalizer matches the numerator
        lsum += bf2f(pk[0]) + bf2f(pk[1]) + bf2f(pk[2]) + bf2f(pk[3]);
        *(us4*)&pT[ar][jb] = pk;
      }
    }
    __syncthreads();  // S2

    // MFMA over this j-tile (K = 64 as 2 x 32)
    #pragma unroll
    for (int kc = 0; kc < 64; kc += 32) {
      bf16x8 a0 = *(const bf16x8*)&pT[R0 + lr][kc + lk * 8];
      bf16x8 a1 = *(const bf16x8*)&pT[R0 + 16 + lr][kc + lk * 8];
      bf16x8 b0 = *(const bf16x8*)&hTl[C0 + lr][kc + lk * 8];
      bf16x8 b1 = *(const bf16x8*)&hTl[C0 + 16 + lr][kc + lk * 8];
      acc[0][0] = __builtin_amdgcn_mfma_f32_16x16x32_bf16(a0, b0, acc[0][0], 0, 0, 0);
      acc[0][1] = __builtin_amdgcn_mfma_f32_16x16x32_bf16(a0, b1, acc[0][1], 0, 0, 0);
      acc[1][0] = __builtin_amdgcn_mfma_f32_16x16x32_bf16(a1, b0, acc[1][0], 0, 0, 0);
      acc[1][1] = __builtin_amdgcn_mfma_f32_16x16x32_bf16(a1, b1, acc[1][1], 0, 0, 0);
    }
    __syncthreads();  // S3
  }

  // row-sum reduction for the softmax denominator
  lred[ar][t & 3] = lsum;
  __syncthreads();
  if (t < 64) invl[t] = 1.0f / (lred[t][0] + lred[t][1] + lred[t][2] + lred[t][3]);
  __syncthreads();

  // epilogue: scale + store
  #pragma unroll
  for (int fa = 0; fa < 2; ++fa) {
    #pragma unroll
    for (int fb = 0; fb < 2; ++fb) {
      #pragma unroll
      for (int reg = 0; reg < 4; ++reg) {
        int row = R0 + fa * 16 + lk * 4 + reg;
        int col = C0 + fb * 16 + lr;
        out[(size_t)(i0 + row) * out_stride + ocol0 + col] = acc[fa][fb][reg] * invl[row];
      }
    }
  }
}

// ---------------------------------------------------------------------------
// elu + log_softmax over 128 classes; one block (128 thr) per row
// ---------------------------------------------------------------------------
__global__ __launch_bounds__(128) void finalize_kernel(
    const float* __restrict__ out2, float* __restrict__ dout) {
  const int i = blockIdx.x, t = threadIdx.x;
  float v = out2[(size_t)i * 128 + t];
  float e = v > 0.f ? v : (__expf(v) - 1.0f);
  float mx = e;
  #pragma unroll
  for (int off = 32; off; off >>= 1) mx = fmaxf(mx, __shfl_xor(mx, off));
  __shared__ float r2[2];
  if ((t & 63) == 0) r2[t >> 6] = mx;
  __syncthreads();
  mx = fmaxf(r2[0], r2[1]);
  float s = __expf(e - mx);
  #pragma unroll
  for (int off = 32; off; off >>= 1) s += __shfl_xor(s, off);
  __shared__ float s2[2];
  if ((t & 63) == 0) s2[t >> 6] = s;
  __syncthreads();
  float sum = s2[0] + s2[1];
  dout[(size_t)i * 128 + t] = e - mx - __logf(sum);
}

// ---------------------------------------------------------------------------
extern "C" void kernel_launch(void* const* d_in, const int* in_sizes, int n_in,
                              void* d_out, int out_size, void* d_ws, size_t ws_size,
                              hipStream_t stream) {
  const float* x     = (const float*)d_in[0];
  const int*   adj   = (const int*)d_in[1];
  const float* W     = (const float*)d_in[2];
  const float* a     = (const float*)d_in[3];
  const float* W_out = (const float*)d_in[4];
  const float* a_out = (const float*)d_in[5];
  float* out = (float*)d_out;

  float* ws   = (float*)d_ws;
  float* h1   = ws;                        // 8*4096*64  = 2,097,152 f
  float* xcat = h1 + 8 * 4096 * 64;        // 4096*512   = 2,097,152 f
  float* h2   = xcat + 4096 * 512;         // 4096*128   =   524,288 f
  float* out2 = h2 + 4096 * 128;           // 4096*128   =   524,288 f
  float* fi1  = out2 + 4096 * 128;         // 32,768
  float* fj1  = fi1 + 8 * 4096;
  float* fi2  = fj1 + 8 * 4096;            // 4,096
  float* fj2  = fi2 + 4096;
  short* hT1  = (short*)(fj2 + 4096);      // 8*64*4096 bf16 = 2,097,152 sh
  short* hT2  = hT1 + 8 * 64 * 4096;       // 128*4096 bf16  =   524,288 sh

  // ---- layer 1 ----
  gemm64<<<dim3(64, 1, 8), 256, 0, stream>>>(x, W, h1, 4096, 512, 64);
  transpose_bf16<<<dim3(64, 1, 8), 256, 0, stream>>>(h1, hT1, 64);
  fifj_kernel<64><<<dim3(8 * 4096 / 4), 256, 0, stream>>>(h1, a, fi1, fj1);
  pv_mfma<<<dim3(64, 1, 8), 256, 0, stream>>>(hT1, fi1, fj1, adj, xcat, 512);

  // ---- layer 2 ----
  gemm64<<<dim3(64, 2, 1), 256, 0, stream>>>(xcat, W_out, h2, 4096, 512, 128);
  transpose_bf16<<<dim3(64, 2, 1), 256, 0, stream>>>(h2, hT2, 128);
  fifj_kernel<128><<<dim3(4096 / 4), 256, 0, stream>>>(h2, a_out, fi2, fj2);
  pv_mfma<<<dim3(64, 2, 1), 256, 0, stream>>>(hT2, fi2, fj2, adj, out2, 128);

  // ---- elu + log_softmax ----
  finalize_kernel<<<dim3(4096), 128, 0, stream>>>(out2, out);
}

// Round 4
// 289.588 us; speedup vs baseline: 2.8331x; 1.6373x over previous
//
#include <hip/hip_runtime.h>
#include <hip/hip_bf16.h>

#define NNODE 4096

typedef __attribute__((ext_vector_type(8))) short bf16x8;
typedef __attribute__((ext_vector_type(4))) float f32x4;
typedef __attribute__((ext_vector_type(8))) unsigned short us8;

__device__ __forceinline__ float leaky(float x) { return x > 0.0f ? x : 0.2f * x; }

__device__ __forceinline__ unsigned short f2bf(float x) {
  __hip_bfloat16 b = __float2bfloat16(x);
  return __builtin_bit_cast(unsigned short, b);
}

// ---------------------------------------------------------------------------
// adj (0/1 int32) -> bitmask, one u64 per 64 columns. One wave -> one word.
// ---------------------------------------------------------------------------
__global__ __launch_bounds__(256) void packadj(
    const int* __restrict__ adj, unsigned long long* __restrict__ mask) {
  size_t wid = (size_t)blockIdx.x * 4 + (threadIdx.x >> 6);
  int v = adj[wid * 64 + (threadIdx.x & 63)];
  unsigned long long b = __ballot(v != 0);
  if ((threadIdx.x & 63) == 0) mask[wid] = b;
}

// ---------------------------------------------------------------------------
// GEMM: C[h] = A @ B[h]. fp32, 64x64 tile, 4x4 micro. grid = (M/64, N/64, H)
// ---------------------------------------------------------------------------
__global__ __launch_bounds__(256) void gemm64(
    const float* __restrict__ A, const float* __restrict__ B, float* __restrict__ C,
    int M, int K, int Nfull) {
  __shared__ float Ast[64][68];  // [k][row]
  __shared__ float Bs[64][68];   // [k][col]
  const int t  = threadIdx.x;
  const int i0 = blockIdx.x * 64;
  const int c0 = blockIdx.y * 64;
  const int h  = blockIdx.z;
  const float* Bh = B + (size_t)h * K * Nfull;
  float*       Ch = C + (size_t)h * M * Nfull;
  const int tx = t & 15, ty = t >> 4;
  const int lrow = t >> 4;
  const int lcol = (t & 15) * 4;
  float acc[4][4] = {};

  for (int k0 = 0; k0 < K; k0 += 64) {
    #pragma unroll
    for (int s = 0; s < 4; ++s) {
      int r = lrow + s * 16;
      float4 av = *(const float4*)&A[(size_t)(i0 + r) * K + k0 + lcol];
      Ast[lcol + 0][r] = av.x;
      Ast[lcol + 1][r] = av.y;
      Ast[lcol + 2][r] = av.z;
      Ast[lcol + 3][r] = av.w;
      float4 bv = *(const float4*)&Bh[(size_t)(k0 + r) * Nfull + c0 + lcol];
      *(float4*)&Bs[r][lcol] = bv;
    }
    __syncthreads();
    #pragma unroll 8
    for (int k = 0; k < 64; ++k) {
      float4 a4 = *(const float4*)&Ast[k][ty * 4];
      float4 b4 = *(const float4*)&Bs[k][tx * 4];
      acc[0][0] += a4.x * b4.x; acc[0][1] += a4.x * b4.y; acc[0][2] += a4.x * b4.z; acc[0][3] += a4.x * b4.w;
      acc[1][0] += a4.y * b4.x; acc[1][1] += a4.y * b4.y; acc[1][2] += a4.y * b4.z; acc[1][3] += a4.y * b4.w;
      acc[2][0] += a4.z * b4.x; acc[2][1] += a4.z * b4.y; acc[2][2] += a4.z * b4.z; acc[2][3] += a4.z * b4.w;
      acc[3][0] += a4.w * b4.x; acc[3][1] += a4.w * b4.y; acc[3][2] += a4.w * b4.z; acc[3][3] += a4.w * b4.w;
    }
    __syncthreads();
  }
  #pragma unroll
  for (int mi = 0; mi < 4; ++mi) {
    #pragma unroll
    for (int ni = 0; ni < 4; ++ni)
      Ch[(size_t)(i0 + ty * 4 + mi) * Nfull + c0 + tx * 4 + ni] = acc[mi][ni];
  }
}

// ---------------------------------------------------------------------------
// transpose + bf16 cast: src [h][n][Fsrc] f32 -> dst [h][Fsrc][n] bf16
// grid = (N/64, Fsrc/64, heads)
// ---------------------------------------------------------------------------
__global__ __launch_bounds__(256) void transpose_bf16(
    const float* __restrict__ src, short* __restrict__ dst, int Fsrc) {
  __shared__ float tile[64][68];
  const int t  = threadIdx.x;
  const int n0 = blockIdx.x * 64, o0 = blockIdx.y * 64;
  const int h  = blockIdx.z;
  const float* S = src + ((size_t)h * NNODE + n0) * Fsrc + o0;
  short* D = dst + ((size_t)h * Fsrc + o0) * NNODE + n0;
  const int r = t >> 2, cs = (t & 3) * 16;
  #pragma unroll
  for (int k2 = 0; k2 < 4; ++k2) {
    float4 v = *(const float4*)&S[(size_t)r * Fsrc + cs + k2 * 4];
    *(float4*)&tile[r][cs + k2 * 4] = v;
  }
  __syncthreads();
  const int o = t >> 2, ns = (t & 3) * 16;
  us8 u0, u1;
  #pragma unroll
  for (int e = 0; e < 8; ++e) u0[e] = f2bf(tile[ns + e][o]);
  #pragma unroll
  for (int e = 0; e < 8; ++e) u1[e] = f2bf(tile[ns + 8 + e][o]);
  *(us8*)&D[(size_t)o * NNODE + ns]     = u0;
  *(us8*)&D[(size_t)o * NNODE + ns + 8] = u1;
}

// ---------------------------------------------------------------------------
// fi[h][n] = h[h][n][:] . a1[h],  fj[h][n] = h[h][n][:] . a2[h]
// ---------------------------------------------------------------------------
template<int F>
__global__ __launch_bounds__(256) void fifj_kernel(
    const float* __restrict__ hbuf, const float* __restrict__ avec,
    float* __restrict__ fi, float* __restrict__ fj) {
  const int gid  = blockIdx.x * 4 + (threadIdx.x >> 6);
  const int lane = threadIdx.x & 63;
  const int h = gid >> 12;
  const int n = gid & 4095;
  const float* hrow = hbuf + ((size_t)h * NNODE + n) * F;
  const float* a1 = avec + h * 2 * F;
  const float* a2 = a1 + F;
  float v1 = 0.f, v2 = 0.f;
  #pragma unroll
  for (int e = lane; e < F; e += 64) {
    float xv = hrow[e];
    v1 += xv * a1[e];
    v2 += xv * a2[e];
  }
  #pragma unroll
  for (int off = 32; off; off >>= 1) {
    v1 += __shfl_xor(v1, off);
    v2 += __shfl_xor(v2, off);
  }
  if (lane == 0) {
    fi[h * NNODE + n] = v1;
    fj[h * NNODE + n] = v2;
  }
}

// ---------------------------------------------------------------------------
// PV split-j with MFMA (bf16):
//   p_ij = bit ? exp(leaky(fi_i + fj_j)) : 0   (no max-subtraction: fp32-safe)
// Each block: 64 i-rows x (OT*64) o-cols x JLEN j-strip; writes partial
// numerator [64][OT*64] and partial row-sum l[64] (normalized by combiner).
// grid = (NNODE/64, NCHUNK, NH), 256 thr (4 waves, 2x2), 2x2 frags/wave/ot.
// ---------------------------------------------------------------------------
template<int OT, int JLEN>
__global__ __launch_bounds__(256) void pv_split(
    const short* __restrict__ hT, const float* __restrict__ fi,
    const float* __restrict__ fj, const unsigned long long* __restrict__ mask,
    float* __restrict__ pnum, float* __restrict__ pl, int Fh) {
  __shared__ short pT[64][72];          // [i-row][j] bf16
  __shared__ short hTl[OT][64][72];     // [ot][o-col][j] bf16
  __shared__ float fjL[64];
  __shared__ float lred[64][4];

  const int t      = threadIdx.x;
  const int lane   = t & 63;
  const int w      = t >> 6;
  const int i0     = blockIdx.x * 64;
  const int chunk  = blockIdx.y;
  const int nchunk = gridDim.y;
  const int h      = blockIdx.z;
  const int hN     = h * NNODE;
  const short* hTs = hT + (size_t)h * Fh * NNODE;

  const int R0 = (w >> 1) * 32;
  const int C0 = (w & 1) * 32;
  const int lr = lane & 15;
  const int lk = lane >> 4;

  const int ar = t >> 2;                // phase-A row 0..63
  const int jc = (t & 3) * 16;          // phase-A j chunk within tile
  const float fir = fi[hN + i0 + ar];
  const unsigned short* mrow =
      (const unsigned short*)mask + (size_t)(i0 + ar) * (NNODE / 16);

  f32x4 acc[OT][2][2] = {};
  float lsum = 0.0f;

  const int jbase = chunk * JLEN;
  for (int jt = 0; jt < JLEN; jt += 64) {
    const int j0 = jbase + jt;
    // stage hT tiles (OT x 64o x 64j) + fjL
    {
      const int o = t >> 2, seg = t & 3;
      #pragma unroll
      for (int ot = 0; ot < OT; ++ot) {
        const short* src = hTs + (size_t)(ot * 64 + o) * NNODE + j0 + seg * 16;
        float4 v0 = *(const float4*)(src);
        float4 v1 = *(const float4*)(src + 8);
        *(float4*)&hTl[ot][o][seg * 16]     = v0;
        *(float4*)&hTl[ot][o][seg * 16 + 8] = v1;
      }
    }
    if (t < 64) fjL[t] = fj[hN + j0 + t];
    __syncthreads();  // S1

    // phase A: p tile -> pT (bf16); 16 j's per thread
    {
      unsigned int mb = mrow[(j0 + jc) >> 4];
      unsigned short pk[16];
      #pragma unroll
      for (int g = 0; g < 4; ++g) {
        float4 f4 = *(const float4*)&fjL[jc + g * 4];
        float s0 = fir + f4.x, s1 = fir + f4.y, s2 = fir + f4.z, s3 = fir + f4.w;
        float e0 = __expf(s0 > 0.f ? s0 : 0.2f * s0);
        float e1 = __expf(s1 > 0.f ? s1 : 0.2f * s1);
        float e2 = __expf(s2 > 0.f ? s2 : 0.2f * s2);
        float e3 = __expf(s3 > 0.f ? s3 : 0.2f * s3);
        float p0 = (mb & (1u << (4 * g + 0))) ? e0 : 0.f;
        float p1 = (mb & (1u << (4 * g + 1))) ? e1 : 0.f;
        float p2 = (mb & (1u << (4 * g + 2))) ? e2 : 0.f;
        float p3 = (mb & (1u << (4 * g + 3))) ? e3 : 0.f;
        lsum += p0 + p1 + p2 + p3;
        pk[4 * g + 0] = f2bf(p0); pk[4 * g + 1] = f2bf(p1);
        pk[4 * g + 2] = f2bf(p2); pk[4 * g + 3] = f2bf(p3);
      }
      *(us8*)&pT[ar][jc]     = *(const us8*)&pk[0];
      *(us8*)&pT[ar][jc + 8] = *(const us8*)&pk[8];
    }
    __syncthreads();  // S2

    // MFMA over this j-tile (K = 64 as 2 x 32)
    #pragma unroll
    for (int kc = 0; kc < 64; kc += 32) {
      bf16x8 a0 = *(const bf16x8*)&pT[R0 + lr][kc + lk * 8];
      bf16x8 a1 = *(const bf16x8*)&pT[R0 + 16 + lr][kc + lk * 8];
      #pragma unroll
      for (int ot = 0; ot < OT; ++ot) {
        bf16x8 b0 = *(const bf16x8*)&hTl[ot][C0 + lr][kc + lk * 8];
        bf16x8 b1 = *(const bf16x8*)&hTl[ot][C0 + 16 + lr][kc + lk * 8];
        acc[ot][0][0] = __builtin_amdgcn_mfma_f32_16x16x32_bf16(a0, b0, acc[ot][0][0], 0, 0, 0);
        acc[ot][0][1] = __builtin_amdgcn_mfma_f32_16x16x32_bf16(a0, b1, acc[ot][0][1], 0, 0, 0);
        acc[ot][1][0] = __builtin_amdgcn_mfma_f32_16x16x32_bf16(a1, b0, acc[ot][1][0], 0, 0, 0);
        acc[ot][1][1] = __builtin_amdgcn_mfma_f32_16x16x32_bf16(a1, b1, acc[ot][1][1], 0, 0, 0);
      }
    }
    __syncthreads();  // S3
  }

  // partial row-sum of p
  lred[ar][t & 3] = lsum;
  __syncthreads();
  if (t < 64)
    pl[(size_t)(h * nchunk + chunk) * NNODE + i0 + t] =
        lred[t][0] + lred[t][1] + lred[t][2] + lred[t][3];

  // partial numerator
  float* pout = pnum + ((size_t)(h * nchunk + chunk) * NNODE + i0) * (OT * 64);
  #pragma unroll
  for (int ot = 0; ot < OT; ++ot) {
    #pragma unroll
    for (int fa = 0; fa < 2; ++fa) {
      #pragma unroll
      for (int fb = 0; fb < 2; ++fb) {
        #pragma unroll
        for (int reg = 0; reg < 4; ++reg) {
          int row = R0 + fa * 16 + lk * 4 + reg;
          int col = ot * 64 + C0 + fb * 16 + lr;
          pout[(size_t)row * (OT * 64) + col] = acc[ot][fa][fb][reg];
        }
      }
    }
  }
}

// ---------------------------------------------------------------------------
// combine L1: xcat[n][h*64+o] = sum_c pnum[(h*NC+c)][n][o] / sum_c pl[h*NC+c][n]
// grid = NNODE, 256 thr (each 2 outputs of the 512)
// ---------------------------------------------------------------------------
template<int NC>
__global__ __launch_bounds__(256) void combine1(
    const float* __restrict__ pnum, const float* __restrict__ pl,
    float* __restrict__ xcat) {
  const int n = blockIdx.x, t = threadIdx.x;
  #pragma unroll
  for (int rep = 0; rep < 2; ++rep) {
    int col = t + rep * 256;
    int h = col >> 6, o = col & 63;
    float s = 0.f, L = 0.f;
    #pragma unroll
    for (int c = 0; c < NC; ++c) {
      s += pnum[((size_t)(h * NC + c) * NNODE + n) * 64 + o];
      L += pl[(size_t)(h * NC + c) * NNODE + n];
    }
    xcat[(size_t)n * 512 + col] = s / L;
  }
}

// ---------------------------------------------------------------------------
// combine L2 + elu + log_softmax. grid = NNODE, 128 thr (one per class)
// ---------------------------------------------------------------------------
__global__ __launch_bounds__(128) void combine2_final(
    const float* __restrict__ pnum, const float* __restrict__ pl,
    float* __restrict__ dout) {
  const int n = blockIdx.x, t = threadIdx.x;
  float s = 0.f, L = 0.f;
  #pragma unroll
  for (int c = 0; c < 8; ++c) {
    s += pnum[((size_t)c * NNODE + n) * 128 + t];
    L += pl[(size_t)c * NNODE + n];
  }
  float v = s / L;
  float e = v > 0.f ? v : (__expf(v) - 1.0f);
  float mx = e;
  #pragma unroll
  for (int off = 32; off; off >>= 1) mx = fmaxf(mx, __shfl_xor(mx, off));
  __shared__ float r2[2];
  if ((t & 63) == 0) r2[t >> 6] = mx;
  __syncthreads();
  mx = fmaxf(r2[0], r2[1]);
  float sm = __expf(e - mx);
  #pragma unroll
  for (int off = 32; off; off >>= 1) sm += __shfl_xor(sm, off);
  __shared__ float s2[2];
  if ((t & 63) == 0) s2[t >> 6] = sm;
  __syncthreads();
  float sum = s2[0] + s2[1];
  dout[(size_t)n * 128 + t] = e - mx - __logf(sum);
}

// ---------------------------------------------------------------------------
// Workspace layout (floats from base; all offsets 4096-multiples => 16B align)
//   mask : [0,        524288)   2 MB bitmask (persistent)
//   h    : [524288,  2621440)   h1 (L1) then reused as h2 (L2)
//   xcat : [2621440, 4718592)
//   hT   : [4718592, 5767168)   hT1 then reused as hT2
//   pnum : [5767168, 9961472)   pnum1 (8h x 2c x 4096 x 64) == pnum2 (8c x 4096 x 128)
//   pl   : [9961472, 10092544)
//   fi1/fj1/fi2/fj2: tail (tiny)
// Peak ~40.7 MB.
// ---------------------------------------------------------------------------
extern "C" void kernel_launch(void* const* d_in, const int* in_sizes, int n_in,
                              void* d_out, int out_size, void* d_ws, size_t ws_size,
                              hipStream_t stream) {
  const float* x     = (const float*)d_in[0];
  const int*   adj   = (const int*)d_in[1];
  const float* W     = (const float*)d_in[2];
  const float* a     = (const float*)d_in[3];
  const float* W_out = (const float*)d_in[4];
  const float* a_out = (const float*)d_in[5];
  float* out = (float*)d_out;

  float* ws = (float*)d_ws;
  unsigned long long* mask = (unsigned long long*)ws;
  float* hbuf = ws + 524288;
  float* xcat = hbuf + 2097152;
  short* hT   = (short*)(xcat + 2097152);
  float* pnum = (float*)(((short*)hT) + 2097152);
  float* pl   = pnum + 4194304;
  float* fi1  = pl + 131072;
  float* fj1  = fi1 + 32768;
  float* fi2  = fj1 + 32768;
  float* fj2  = fi2 + 4096;

  packadj<<<dim3(NNODE * NNODE / 64 / 4), 256, 0, stream>>>(adj, mask);

  // ---- layer 1 ----
  gemm64<<<dim3(64, 1, 8), 256, 0, stream>>>(x, W, hbuf, 4096, 512, 64);
  transpose_bf16<<<dim3(64, 1, 8), 256, 0, stream>>>(hbuf, hT, 64);
  fifj_kernel<64><<<dim3(8 * 4096 / 4), 256, 0, stream>>>(hbuf, a, fi1, fj1);
  pv_split<1, 2048><<<dim3(64, 2, 8), 256, 0, stream>>>(hT, fi1, fj1, mask, pnum, pl, 64);
  combine1<2><<<dim3(NNODE), 256, 0, stream>>>(pnum, pl, xcat);

  // ---- layer 2 ----
  gemm64<<<dim3(64, 2, 1), 256, 0, stream>>>(xcat, W_out, hbuf, 4096, 512, 128);
  transpose_bf16<<<dim3(64, 2, 1), 256, 0, stream>>>(hbuf, hT, 128);
  fifj_kernel<128><<<dim3(4096 / 4), 256, 0, stream>>>(hbuf, a_out, fi2, fj2);
  pv_split<2, 512><<<dim3(64, 8, 1), 256, 0, stream>>>(hT, fi2, fj2, mask, pnum, pl, 128);
  combine2_final<<<dim3(NNODE), 128, 0, stream>>>(pnum, pl, out);
}

// Round 7
// 273.168 us; speedup vs baseline: 3.0034x; 1.0601x over previous
//
#include <hip/hip_runtime.h>
#include <hip/hip_bf16.h>

#define NNODE 4096

typedef __attribute__((ext_vector_type(8))) short bf16x8;
typedef __attribute__((ext_vector_type(4))) float f32x4;
typedef __attribute__((ext_vector_type(8))) unsigned short us8;

__device__ __forceinline__ unsigned short f2bf(float x) {
  __hip_bfloat16 b = __float2bfloat16(x);
  return __builtin_bit_cast(unsigned short, b);
}

// ---------------------------------------------------------------------------
// adj (0/1 int32) -> bitmask, one u64 per 64 columns. One wave -> one word.
// ---------------------------------------------------------------------------
__global__ __launch_bounds__(256) void packadj(
    const int* __restrict__ adj, unsigned long long* __restrict__ mask) {
  size_t wid = (size_t)blockIdx.x * 4 + (threadIdx.x >> 6);
  int v = adj[wid * 64 + (threadIdx.x & 63)];
  unsigned long long b = __ballot(v != 0);
  if ((threadIdx.x & 63) == 0) mask[wid] = b;
}

// ---------------------------------------------------------------------------
// transpose + bf16 cast: src [h][Nr][Fsrc] f32 -> dst [h][Fsrc][Nr] bf16
// grid = (Nr/64, Fsrc/64, heads)
// ---------------------------------------------------------------------------
__global__ __launch_bounds__(256) void transpose_bf16(
    const float* __restrict__ src, short* __restrict__ dst, int Nr, int Fsrc) {
  __shared__ float tile[64][68];
  const int t  = threadIdx.x;
  const int n0 = blockIdx.x * 64, o0 = blockIdx.y * 64;
  const int h  = blockIdx.z;
  const float* S = src + ((size_t)h * Nr + n0) * Fsrc + o0;
  short* D = dst + ((size_t)h * Fsrc + o0) * Nr + n0;
  const int r = t >> 2, cs = (t & 3) * 16;
  #pragma unroll
  for (int k2 = 0; k2 < 4; ++k2) {
    float4 v = *(const float4*)&S[(size_t)r * Fsrc + cs + k2 * 4];
    *(float4*)&tile[r][cs + k2 * 4] = v;
  }
  __syncthreads();
  const int o = t >> 2, ns = (t & 3) * 16;
  us8 u0, u1;
  #pragma unroll
  for (int e = 0; e < 8; ++e) u0[e] = f2bf(tile[ns + e][o]);
  #pragma unroll
  for (int e = 0; e < 8; ++e) u1[e] = f2bf(tile[ns + 8 + e][o]);
  *(us8*)&D[(size_t)o * Nr + ns]     = u0;
  *(us8*)&D[(size_t)o * Nr + ns + 8] = u1;
}

// ---------------------------------------------------------------------------
// GEMM via MFMA: C[h] = A @ B[h], A MxK f32 (cast to bf16 in staging, shared
// across heads), Wt bf16 [h][Nfull][K] (pre-transposed) read from global.
// 64x64 tile, 4 waves (2x2), 2x2 frags of 16x16, BK=64, B double-buffered.
// grid = (M/64, Nfull/64, H)
// ---------------------------------------------------------------------------
__global__ __launch_bounds__(256) void gemm_mfma(
    const float* __restrict__ A, const short* __restrict__ Wt,
    float* __restrict__ C, int M, int K, int Nfull) {
  __shared__ short As[64][72];   // [row][k] bf16
  const int t  = threadIdx.x;
  const int lane = t & 63;
  const int w  = t >> 6;
  const int i0 = blockIdx.x * 64;
  const int c0 = blockIdx.y * 64;
  const int h  = blockIdx.z;
  const short* Bh = Wt + ((size_t)h * Nfull + c0) * K;
  float*       Ch = C + (size_t)h * M * Nfull;   // << the round-5/6 bug: was missing

  const int R0 = (w >> 1) * 32;
  const int C0 = (w & 1) * 32;
  const int lr = lane & 15;
  const int lk = lane >> 4;

  const int arow = t >> 2;         // A-staging row
  const int aseg = (t & 3) * 16;   // A-staging k chunk

  f32x4 acc[2][2] = {};

  const short* b00p = &Bh[(size_t)(C0 + lr) * K + lk * 8];
  const short* b10p = &Bh[(size_t)(C0 + 16 + lr) * K + lk * 8];

  bf16x8 bc[4];
  bc[0] = *(const bf16x8*)(b00p);
  bc[1] = *(const bf16x8*)(b10p);
  bc[2] = *(const bf16x8*)(b00p + 32);
  bc[3] = *(const bf16x8*)(b10p + 32);

  for (int k0 = 0; k0 < K; k0 += 64) {
    // stage A tile (64 x 64) as bf16
    {
      const float* src = &A[(size_t)(i0 + arow) * K + k0 + aseg];
      float4 v0 = *(const float4*)(src);
      float4 v1 = *(const float4*)(src + 4);
      float4 v2 = *(const float4*)(src + 8);
      float4 v3 = *(const float4*)(src + 12);
      us8 u0, u1;
      u0[0] = f2bf(v0.x); u0[1] = f2bf(v0.y); u0[2] = f2bf(v0.z); u0[3] = f2bf(v0.w);
      u0[4] = f2bf(v1.x); u0[5] = f2bf(v1.y); u0[6] = f2bf(v1.z); u0[7] = f2bf(v1.w);
      u1[0] = f2bf(v2.x); u1[1] = f2bf(v2.y); u1[2] = f2bf(v2.z); u1[3] = f2bf(v2.w);
      u1[4] = f2bf(v3.x); u1[5] = f2bf(v3.y); u1[6] = f2bf(v3.z); u1[7] = f2bf(v3.w);
      *(us8*)&As[arow][aseg]     = u0;
      *(us8*)&As[arow][aseg + 8] = u1;
    }
    // prefetch next iteration's B fragments
    bf16x8 bn[4];
    {
      int kn = (k0 + 64 < K) ? (k0 + 64) : k0;
      bn[0] = *(const bf16x8*)(b00p + kn);
      bn[1] = *(const bf16x8*)(b10p + kn);
      bn[2] = *(const bf16x8*)(b00p + kn + 32);
      bn[3] = *(const bf16x8*)(b10p + kn + 32);
    }
    __syncthreads();
    #pragma unroll
    for (int kc = 0; kc < 64; kc += 32) {
      bf16x8 a0 = *(const bf16x8*)&As[R0 + lr][kc + lk * 8];
      bf16x8 a1 = *(const bf16x8*)&As[R0 + 16 + lr][kc + lk * 8];
      bf16x8 b0 = bc[(kc >> 5) * 2 + 0];
      bf16x8 b1 = bc[(kc >> 5) * 2 + 1];
      acc[0][0] = __builtin_amdgcn_mfma_f32_16x16x32_bf16(a0, b0, acc[0][0], 0, 0, 0);
      acc[0][1] = __builtin_amdgcn_mfma_f32_16x16x32_bf16(a0, b1, acc[0][1], 0, 0, 0);
      acc[1][0] = __builtin_amdgcn_mfma_f32_16x16x32_bf16(a1, b0, acc[1][0], 0, 0, 0);
      acc[1][1] = __builtin_amdgcn_mfma_f32_16x16x32_bf16(a1, b1, acc[1][1], 0, 0, 0);
    }
    bc[0] = bn[0]; bc[1] = bn[1]; bc[2] = bn[2]; bc[3] = bn[3];
    __syncthreads();
  }

  #pragma unroll
  for (int fa = 0; fa < 2; ++fa) {
    #pragma unroll
    for (int fb = 0; fb < 2; ++fb) {
      #pragma unroll
      for (int reg = 0; reg < 4; ++reg) {
        int row = R0 + fa * 16 + lk * 4 + reg;
        int col = C0 + fb * 16 + lr;
        Ch[(size_t)(i0 + row) * Nfull + c0 + col] = acc[fa][fb][reg];
      }
    }
  }
}

// ---------------------------------------------------------------------------
// wa[h][0][k] = sum_o W[h][k][o]*a[h][o];  wa[h][1][k] = sum_o W[h][k][o]*a[h][F+o]
// fp32 exact logit path (associativity: fi = x @ (W@a1)). One wave per (h,k).
// ---------------------------------------------------------------------------
template<int F>
__global__ __launch_bounds__(256) void wa_kernel(
    const float* __restrict__ W, const float* __restrict__ a,
    float* __restrict__ wa) {
  const int gid  = blockIdx.x * 4 + (threadIdx.x >> 6);  // h*512 + k
  const int lane = threadIdx.x & 63;
  const int h = gid >> 9;
  const int k = gid & 511;
  const float* wrow = W + ((size_t)h * 512 + k) * F;
  const float* ah = a + h * 2 * F;
  float v1 = 0.f, v2 = 0.f;
  #pragma unroll
  for (int o = lane; o < F; o += 64) {
    float wv = wrow[o];
    v1 += wv * ah[o];
    v2 += wv * ah[F + o];
  }
  #pragma unroll
  for (int off = 32; off; off >>= 1) {
    v1 += __shfl_xor(v1, off);
    v2 += __shfl_xor(v2, off);
  }
  if (lane == 0) {
    wa[((size_t)h * 2 + 0) * 512 + k] = v1;
    wa[((size_t)h * 2 + 1) * 512 + k] = v2;
  }
}

// ---------------------------------------------------------------------------
// fi[h][n] = X[n][:512] . wa[h][0], fj likewise with wa[h][1]; plus factored
// exps eiP=exp(fi), eiN=exp(.2fi), ejP=exp(fj), ejN=exp(.2fj). fp32 exact.
// ---------------------------------------------------------------------------
template<int NH>
__global__ __launch_bounds__(256) void fidot_kernel(
    const float* __restrict__ X, const float* __restrict__ wa,
    float* __restrict__ fi, float* __restrict__ fj,
    float* __restrict__ eiP, float* __restrict__ eiN,
    float* __restrict__ ejP, float* __restrict__ ejN) {
  const int gid  = blockIdx.x * 4 + (threadIdx.x >> 6);
  const int lane = threadIdx.x & 63;
  const int h = gid >> 12;
  const int n = gid & 4095;
  const float* xr = X + (size_t)n * 512;
  const float* w1 = wa + (size_t)h * 2 * 512;
  const float* w2 = w1 + 512;
  float v1 = 0.f, v2 = 0.f;
  #pragma unroll
  for (int it = 0; it < 8; ++it) {
    int k = lane + it * 64;
    float xv = xr[k];
    v1 += xv * w1[k];
    v2 += xv * w2[k];
  }
  #pragma unroll
  for (int off = 32; off; off >>= 1) {
    v1 += __shfl_xor(v1, off);
    v2 += __shfl_xor(v2, off);
  }
  if (lane == 0) {
    int idx = h * NNODE + n;
    fi[idx] = v1;
    fj[idx] = v2;
    eiP[idx] = __expf(v1);
    eiN[idx] = __expf(0.2f * v1);
    ejP[idx] = __expf(v2);
    ejN[idx] = __expf(0.2f * v2);
  }
}

// ---------------------------------------------------------------------------
// PV split-j with MFMA (bf16), factored exp:
//   p_ij = bit ? (fj_j > -fi_i ? eiP_i*ejP_j : eiN_i*ejN_j) : 0
// grid = (NNODE/64, NCHUNK, NH)
// ---------------------------------------------------------------------------
template<int OT, int JLEN>
__global__ __launch_bounds__(256) void pv_split(
    const short* __restrict__ hT, const float* __restrict__ fi,
    const float* __restrict__ eiP, const float* __restrict__ eiN,
    const float* __restrict__ fj, const float* __restrict__ ejP,
    const float* __restrict__ ejN, const unsigned long long* __restrict__ mask,
    float* __restrict__ pnum, float* __restrict__ pl, int Fh) {
  __shared__ short pT[64][72];          // [i-row][j] bf16
  __shared__ short hTl[OT][64][72];     // [ot][o-col][j] bf16
  __shared__ float fjL[64], ejPL[64], ejNL[64];
  __shared__ float lred[64][4];

  const int t      = threadIdx.x;
  const int lane   = t & 63;
  const int w      = t >> 6;
  const int i0     = blockIdx.x * 64;
  const int chunk  = blockIdx.y;
  const int nchunk = gridDim.y;
  const int h      = blockIdx.z;
  const int hN     = h * NNODE;
  const short* hTs = hT + (size_t)h * Fh * NNODE;

  const int R0 = (w >> 1) * 32;
  const int C0 = (w & 1) * 32;
  const int lr = lane & 15;
  const int lk = lane >> 4;

  const int ar = t >> 2;                // phase-A row 0..63
  const int jc = (t & 3) * 16;          // phase-A j chunk within tile
  const float thr  = -fi[hN + i0 + ar];
  const float eiPr = eiP[hN + i0 + ar];
  const float eiNr = eiN[hN + i0 + ar];
  const unsigned short* mrow =
      (const unsigned short*)mask + (size_t)(i0 + ar) * (NNODE / 16);

  f32x4 acc[OT][2][2] = {};
  float lsum = 0.0f;

  const int jbase = chunk * JLEN;
  for (int jt = 0; jt < JLEN; jt += 64) {
    const int j0 = jbase + jt;
    // stage hT tiles (OT x 64o x 64j) + per-j vectors
    {
      const int o = t >> 2, seg = t & 3;
      #pragma unroll
      for (int ot = 0; ot < OT; ++ot) {
        const short* src = hTs + (size_t)(ot * 64 + o) * NNODE + j0 + seg * 16;
        float4 v0 = *(const float4*)(src);
        float4 v1 = *(const float4*)(src + 8);
        *(float4*)&hTl[ot][o][seg * 16]     = v0;
        *(float4*)&hTl[ot][o][seg * 16 + 8] = v1;
      }
    }
    if (t < 64) {
      fjL[t]  = fj[hN + j0 + t];
      ejPL[t] = ejP[hN + j0 + t];
      ejNL[t] = ejN[hN + j0 + t];
    }
    __syncthreads();  // S1

    // phase A: p tile -> pT (bf16); 16 j's per thread, no transcendentals
    {
      unsigned int mb = mrow[(j0 + jc) >> 4];
      unsigned short pk[16];
      #pragma unroll
      for (int g = 0; g < 4; ++g) {
        float4 f4 = *(const float4*)&fjL[jc + g * 4];
        float4 eP = *(const float4*)&ejPL[jc + g * 4];
        float4 eN = *(const float4*)&ejNL[jc + g * 4];
        float p0 = (f4.x > thr) ? eiPr * eP.x : eiNr * eN.x;
        float p1 = (f4.y > thr) ? eiPr * eP.y : eiNr * eN.y;
        float p2 = (f4.z > thr) ? eiPr * eP.z : eiNr * eN.z;
        float p3 = (f4.w > thr) ? eiPr * eP.w : eiNr * eN.w;
        p0 = (mb & (1u << (4 * g + 0))) ? p0 : 0.f;
        p1 = (mb & (1u << (4 * g + 1))) ? p1 : 0.f;
        p2 = (mb & (1u << (4 * g + 2))) ? p2 : 0.f;
        p3 = (mb & (1u << (4 * g + 3))) ? p3 : 0.f;
        lsum += p0 + p1 + p2 + p3;
        pk[4 * g + 0] = f2bf(p0); pk[4 * g + 1] = f2bf(p1);
        pk[4 * g + 2] = f2bf(p2); pk[4 * g + 3] = f2bf(p3);
      }
      *(us8*)&pT[ar][jc]     = *(const us8*)&pk[0];
      *(us8*)&pT[ar][jc + 8] = *(const us8*)&pk[8];
    }
    __syncthreads();  // S2

    // MFMA over this j-tile (K = 64 as 2 x 32)
    #pragma unroll
    for (int kc = 0; kc < 64; kc += 32) {
      bf16x8 a0 = *(const bf16x8*)&pT[R0 + lr][kc + lk * 8];
      bf16x8 a1 = *(const bf16x8*)&pT[R0 + 16 + lr][kc + lk * 8];
      #pragma unroll
      for (int ot = 0; ot < OT; ++ot) {
        bf16x8 b0 = *(const bf16x8*)&hTl[ot][C0 + lr][kc + lk * 8];
        bf16x8 b1 = *(const bf16x8*)&hTl[ot][C0 + 16 + lr][kc + lk * 8];
        acc[ot][0][0] = __builtin_amdgcn_mfma_f32_16x16x32_bf16(a0, b0, acc[ot][0][0], 0, 0, 0);
        acc[ot][0][1] = __builtin_amdgcn_mfma_f32_16x16x32_bf16(a0, b1, acc[ot][0][1], 0, 0, 0);
        acc[ot][1][0] = __builtin_amdgcn_mfma_f32_16x16x32_bf16(a1, b0, acc[ot][1][0], 0, 0, 0);
        acc[ot][1][1] = __builtin_amdgcn_mfma_f32_16x16x32_bf16(a1, b1, acc[ot][1][1], 0, 0, 0);
      }
    }
    __syncthreads();  // S3
  }

  // partial row-sum of p
  lred[ar][t & 3] = lsum;
  __syncthreads();
  if (t < 64)
    pl[(size_t)(h * nchunk + chunk) * NNODE + i0 + t] =
        lred[t][0] + lred[t][1] + lred[t][2] + lred[t][3];

  // partial numerator
  float* pout = pnum + ((size_t)(h * nchunk + chunk) * NNODE + i0) * (OT * 64);
  #pragma unroll
  for (int ot = 0; ot < OT; ++ot) {
    #pragma unroll
    for (int fa = 0; fa < 2; ++fa) {
      #pragma unroll
      for (int fb = 0; fb < 2; ++fb) {
        #pragma unroll
        for (int reg = 0; reg < 4; ++reg) {
          int row = R0 + fa * 16 + lk * 4 + reg;
          int col = ot * 64 + C0 + fb * 16 + lr;
          pout[(size_t)row * (OT * 64) + col] = acc[ot][fa][fb][reg];
        }
      }
    }
  }
}

// ---------------------------------------------------------------------------
// combine L1: xcat[n][h*64+o] = sum_c pnum[(h*NC+c)][n][o] / sum_c pl[h*NC+c][n]
// ---------------------------------------------------------------------------
template<int NC>
__global__ __launch_bounds__(256) void combine1(
    const float* __restrict__ pnum, const float* __restrict__ pl,
    float* __restrict__ xcat) {
  const int n = blockIdx.x, t = threadIdx.x;
  #pragma unroll
  for (int rep = 0; rep < 2; ++rep) {
    int col = t + rep * 256;
    int h = col >> 6, o = col & 63;
    float s = 0.f, L = 0.f;
    #pragma unroll
    for (int c = 0; c < NC; ++c) {
      s += pnum[((size_t)(h * NC + c) * NNODE + n) * 64 + o];
      L += pl[(size_t)(h * NC + c) * NNODE + n];
    }
    xcat[(size_t)n * 512 + col] = s / L;
  }
}

// ---------------------------------------------------------------------------
// combine L2 + elu + log_softmax. grid = NNODE, 128 thr (one per class)
// ---------------------------------------------------------------------------
__global__ __launch_bounds__(128) void combine2_final(
    const float* __restrict__ pnum, const float* __restrict__ pl,
    float* __restrict__ dout) {
  const int n = blockIdx.x, t = threadIdx.x;
  float s = 0.f, L = 0.f;
  #pragma unroll
  for (int c = 0; c < 8; ++c) {
    s += pnum[((size_t)c * NNODE + n) * 128 + t];
    L += pl[(size_t)c * NNODE + n];
  }
  float v = s / L;
  float e = v > 0.f ? v : (__expf(v) - 1.0f);
  float mx = e;
  #pragma unroll
  for (int off = 32; off; off >>= 1) mx = fmaxf(mx, __shfl_xor(mx, off));
  __shared__ float r2[2];
  if ((t & 63) == 0) r2[t >> 6] = mx;
  __syncthreads();
  mx = fmaxf(r2[0], r2[1]);
  float sm = __expf(e - mx);
  #pragma unroll
  for (int off = 32; off; off >>= 1) sm += __shfl_xor(sm, off);
  __shared__ float s2[2];
  if ((t & 63) == 0) s2[t >> 6] = sm;
  __syncthreads();
  float sum = s2[0] + s2[1];
  dout[(size_t)n * 128 + t] = e - mx - __logf(sum);
}

// ---------------------------------------------------------------------------
extern "C" void kernel_launch(void* const* d_in, const int* in_sizes, int n_in,
                              void* d_out, int out_size, void* d_ws, size_t ws_size,
                              hipStream_t stream) {
  const float* x     = (const float*)d_in[0];
  const int*   adj   = (const int*)d_in[1];
  const float* W     = (const float*)d_in[2];
  const float* a     = (const float*)d_in[3];
  const float* W_out = (const float*)d_in[4];
  const float* a_out = (const float*)d_in[5];
  float* out = (float*)d_out;

  float* ws = (float*)d_ws;
  unsigned long long* mask = (unsigned long long*)ws;   // 2 MB
  float* hbuf = ws + 524288;               // 2,097,152 f (h1 then h2)
  float* xcat = hbuf + 2097152;            // 2,097,152 f
  short* hT   = (short*)(xcat + 2097152);  // 2,097,152 sh (hT1 then hT2)
  float* pnum = (float*)(((short*)hT) + 2097152);  // 4,194,304 f
  float* pl   = pnum + 4194304;            // 131,072 f
  short* Wt1  = (short*)(pl + 131072);     // 262,144 sh
  short* Wt2  = Wt1 + 262144;              // 65,536 sh
  float* fi1  = (float*)(Wt2 + 65536);
  float* fj1  = fi1 + 32768;
  float* eiP1 = fj1 + 32768;
  float* eiN1 = eiP1 + 32768;
  float* ejP1 = eiN1 + 32768;
  float* ejN1 = ejP1 + 32768;
  float* fi2  = ejN1 + 32768;
  float* fj2  = fi2 + 4096;
  float* eiP2 = fj2 + 4096;
  float* eiN2 = eiP2 + 4096;
  float* ejP2 = eiN2 + 4096;
  float* ejN2 = ejP2 + 4096;
  float* wa1  = ejN2 + 4096;               // 8*2*512 = 8192 f
  float* wa2  = wa1 + 8192;                // 2*512   = 1024 f

  packadj<<<dim3(NNODE * NNODE / 64 / 4), 256, 0, stream>>>(adj, mask);
  transpose_bf16<<<dim3(8, 1, 8), 256, 0, stream>>>(W, Wt1, 512, 64);
  transpose_bf16<<<dim3(8, 2, 1), 256, 0, stream>>>(W_out, Wt2, 512, 128);
  wa_kernel<64><<<dim3(8 * 512 / 4), 256, 0, stream>>>(W, a, wa1);
  wa_kernel<128><<<dim3(512 / 4), 256, 0, stream>>>(W_out, a_out, wa2);

  // ---- layer 1 ----
  gemm_mfma<<<dim3(64, 1, 8), 256, 0, stream>>>(x, Wt1, hbuf, 4096, 512, 64);
  transpose_bf16<<<dim3(64, 1, 8), 256, 0, stream>>>(hbuf, hT, 4096, 64);
  fidot_kernel<8><<<dim3(8 * 4096 / 4), 256, 0, stream>>>(x, wa1, fi1, fj1, eiP1, eiN1, ejP1, ejN1);
  pv_split<1, 2048><<<dim3(64, 2, 8), 256, 0, stream>>>(hT, fi1, eiP1, eiN1, fj1, ejP1, ejN1, mask, pnum, pl, 64);
  combine1<2><<<dim3(NNODE), 256, 0, stream>>>(pnum, pl, xcat);

  // ---- layer 2 ----
  gemm_mfma<<<dim3(64, 2, 1), 256, 0, stream>>>(xcat, Wt2, hbuf, 4096, 512, 128);
  transpose_bf16<<<dim3(64, 2, 1), 256, 0, stream>>>(hbuf, hT, 4096, 128);
  fidot_kernel<1><<<dim3(4096 / 4), 256, 0, stream>>>(xcat, wa2, fi2, fj2, eiP2, eiN2, ejP2, ejN2);
  pv_split<2, 512><<<dim3(64, 8, 1), 256, 0, stream>>>(hT, fi2, eiP2, eiN2, fj2, ejP2, ejN2, mask, pnum, pl, 128);
  combine2_final<<<dim3(NNODE), 128, 0, stream>>>(pnum, pl, out);
}

// Round 9
// 248.009 us; speedup vs baseline: 3.3080x; 1.1014x over previous
//
#include <hip/hip_runtime.h>
#include <hip/hip_bf16.h>

#define NNODE 4096

typedef __attribute__((ext_vector_type(8))) short bf16x8;
typedef __attribute__((ext_vector_type(4))) float f32x4;
typedef __attribute__((ext_vector_type(4))) unsigned short us4;
typedef __attribute__((ext_vector_type(8))) unsigned short us8;

__device__ __forceinline__ unsigned short f2bf(float x) {
  __hip_bfloat16 b = __float2bfloat16(x);
  return __builtin_bit_cast(unsigned short, b);
}

// ---------------------------------------------------------------------------
// adj (0/1 int32) -> bitmask, one u64 per 64 columns.
// ---------------------------------------------------------------------------
__global__ __launch_bounds__(256) void packadj(
    const int* __restrict__ adj, unsigned long long* __restrict__ mask) {
  size_t wid = (size_t)blockIdx.x * 4 + (threadIdx.x >> 6);
  int v = adj[wid * 64 + (threadIdx.x & 63)];
  unsigned long long b = __ballot(v != 0);
  if ((threadIdx.x & 63) == 0) mask[wid] = b;
}

// ---------------------------------------------------------------------------
// transpose + bf16 cast: src [h][Nr][Fsrc] f32 -> dst [h][Fsrc][Nr] bf16
// (used only for the small W / W_out weights now)
// ---------------------------------------------------------------------------
__global__ __launch_bounds__(256) void transpose_bf16(
    const float* __restrict__ src, short* __restrict__ dst, int Nr, int Fsrc) {
  __shared__ float tile[64][68];
  const int t  = threadIdx.x;
  const int n0 = blockIdx.x * 64, o0 = blockIdx.y * 64;
  const int h  = blockIdx.z;
  const float* S = src + ((size_t)h * Nr + n0) * Fsrc + o0;
  short* D = dst + ((size_t)h * Fsrc + o0) * Nr + n0;
  const int r = t >> 2, cs = (t & 3) * 16;
  #pragma unroll
  for (int k2 = 0; k2 < 4; ++k2) {
    float4 v = *(const float4*)&S[(size_t)r * Fsrc + cs + k2 * 4];
    *(float4*)&tile[r][cs + k2 * 4] = v;
  }
  __syncthreads();
  const int o = t >> 2, ns = (t & 3) * 16;
  us8 u0, u1;
  #pragma unroll
  for (int e = 0; e < 8; ++e) u0[e] = f2bf(tile[ns + e][o]);
  #pragma unroll
  for (int e = 0; e < 8; ++e) u1[e] = f2bf(tile[ns + 8 + e][o]);
  *(us8*)&D[(size_t)o * Nr + ns]     = u0;
  *(us8*)&D[(size_t)o * Nr + ns + 8] = u1;
}

// ---------------------------------------------------------------------------
// GEMM via MFMA, fused transpose epilogue: hT[h][o][n] (bf16) = (A @ B[h])^T.
// A MxK f32 (cast bf16 in staging), Wt bf16 [h][Nfull][K].
// 64x64 tile, 4 waves (2x2), 2x2 frags, BK=64, B double-buffered.
// grid = (M/64, Nfull/64, H)
// ---------------------------------------------------------------------------
__global__ __launch_bounds__(256) void gemm_mfma(
    const float* __restrict__ A, const short* __restrict__ Wt,
    short* __restrict__ hTout, int M, int K, int Nfull) {
  __shared__ short As[64][72];   // [row][k] bf16
  const int t  = threadIdx.x;
  const int lane = t & 63;
  const int w  = t >> 6;
  const int i0 = blockIdx.x * 64;
  const int c0 = blockIdx.y * 64;
  const int h  = blockIdx.z;
  const short* Bh = Wt + ((size_t)h * Nfull + c0) * K;
  short*       Hh = hTout + (size_t)h * Nfull * M;

  const int R0 = (w >> 1) * 32;
  const int C0 = (w & 1) * 32;
  const int lr = lane & 15;
  const int lk = lane >> 4;

  const int arow = t >> 2;
  const int aseg = (t & 3) * 16;

  f32x4 acc[2][2] = {};

  const short* b00p = &Bh[(size_t)(C0 + lr) * K + lk * 8];
  const short* b10p = &Bh[(size_t)(C0 + 16 + lr) * K + lk * 8];

  bf16x8 bc[4];
  bc[0] = *(const bf16x8*)(b00p);
  bc[1] = *(const bf16x8*)(b10p);
  bc[2] = *(const bf16x8*)(b00p + 32);
  bc[3] = *(const bf16x8*)(b10p + 32);

  for (int k0 = 0; k0 < K; k0 += 64) {
    {
      const float* src = &A[(size_t)(i0 + arow) * K + k0 + aseg];
      float4 v0 = *(const float4*)(src);
      float4 v1 = *(const float4*)(src + 4);
      float4 v2 = *(const float4*)(src + 8);
      float4 v3 = *(const float4*)(src + 12);
      us8 u0, u1;
      u0[0] = f2bf(v0.x); u0[1] = f2bf(v0.y); u0[2] = f2bf(v0.z); u0[3] = f2bf(v0.w);
      u0[4] = f2bf(v1.x); u0[5] = f2bf(v1.y); u0[6] = f2bf(v1.z); u0[7] = f2bf(v1.w);
      u1[0] = f2bf(v2.x); u1[1] = f2bf(v2.y); u1[2] = f2bf(v2.z); u1[3] = f2bf(v2.w);
      u1[4] = f2bf(v3.x); u1[5] = f2bf(v3.y); u1[6] = f2bf(v3.z); u1[7] = f2bf(v3.w);
      *(us8*)&As[arow][aseg]     = u0;
      *(us8*)&As[arow][aseg + 8] = u1;
    }
    bf16x8 bn[4];
    {
      int kn = (k0 + 64 < K) ? (k0 + 64) : k0;
      bn[0] = *(const bf16x8*)(b00p + kn);
      bn[1] = *(const bf16x8*)(b10p + kn);
      bn[2] = *(const bf16x8*)(b00p + kn + 32);
      bn[3] = *(const bf16x8*)(b10p + kn + 32);
    }
    __syncthreads();
    #pragma unroll
    for (int kc = 0; kc < 64; kc += 32) {
      bf16x8 a0 = *(const bf16x8*)&As[R0 + lr][kc + lk * 8];
      bf16x8 a1 = *(const bf16x8*)&As[R0 + 16 + lr][kc + lk * 8];
      bf16x8 b0 = bc[(kc >> 5) * 2 + 0];
      bf16x8 b1 = bc[(kc >> 5) * 2 + 1];
      acc[0][0] = __builtin_amdgcn_mfma_f32_16x16x32_bf16(a0, b0, acc[0][0], 0, 0, 0);
      acc[0][1] = __builtin_amdgcn_mfma_f32_16x16x32_bf16(a0, b1, acc[0][1], 0, 0, 0);
      acc[1][0] = __builtin_amdgcn_mfma_f32_16x16x32_bf16(a1, b0, acc[1][0], 0, 0, 0);
      acc[1][1] = __builtin_amdgcn_mfma_f32_16x16x32_bf16(a1, b1, acc[1][1], 0, 0, 0);
    }
    bc[0] = bn[0]; bc[1] = bn[1]; bc[2] = bn[2]; bc[3] = bn[3];
    __syncthreads();
  }

  // epilogue: D row = lk*4+reg (n), col = lr (o); write hT[o][n] bf16 (8B st)
  #pragma unroll
  for (int fa = 0; fa < 2; ++fa) {
    #pragma unroll
    for (int fb = 0; fb < 2; ++fb) {
      int col  = c0 + C0 + fb * 16 + lr;
      int rowb = i0 + R0 + fa * 16 + lk * 4;
      us4 pk;
      #pragma unroll
      for (int reg = 0; reg < 4; ++reg) pk[reg] = f2bf(acc[fa][fb][reg]);
      *(us4*)&Hh[(size_t)col * M + rowb] = pk;
    }
  }
}

// ---------------------------------------------------------------------------
// wa[h][0][k], wa[h][1][k] = sum_o W[h][k][o]*a[h][o or F+o]  (fp32 exact)
// ---------------------------------------------------------------------------
template<int F>
__global__ __launch_bounds__(256) void wa_kernel(
    const float* __restrict__ W, const float* __restrict__ a,
    float* __restrict__ wa) {
  const int gid  = blockIdx.x * 4 + (threadIdx.x >> 6);
  const int lane = threadIdx.x & 63;
  const int h = gid >> 9;
  const int k = gid & 511;
  const float* wrow = W + ((size_t)h * 512 + k) * F;
  const float* ah = a + h * 2 * F;
  float v1 = 0.f, v2 = 0.f;
  #pragma unroll
  for (int o = lane; o < F; o += 64) {
    float wv = wrow[o];
    v1 += wv * ah[o];
    v2 += wv * ah[F + o];
  }
  #pragma unroll
  for (int off = 32; off; off >>= 1) {
    v1 += __shfl_xor(v1, off);
    v2 += __shfl_xor(v2, off);
  }
  if (lane == 0) {
    wa[((size_t)h * 2 + 0) * 512 + k] = v1;
    wa[((size_t)h * 2 + 1) * 512 + k] = v2;
  }
}

// ---------------------------------------------------------------------------
// L1 logits: all 8 heads in one pass over x. wa1 staged in LDS.
// One wave per node. grid = 4096/4.
// ---------------------------------------------------------------------------
__global__ __launch_bounds__(256) void fidot8(
    const float* __restrict__ X, const float* __restrict__ wa,
    float* __restrict__ fi, float* __restrict__ fj,
    float* __restrict__ eiP, float* __restrict__ eiN,
    float* __restrict__ ejP, float* __restrict__ ejN) {
  __shared__ float sw[8192];
  for (int idx = threadIdx.x; idx < 8192; idx += 256) sw[idx] = wa[idx];
  __syncthreads();
  const int n    = blockIdx.x * 4 + (threadIdx.x >> 6);
  const int lane = threadIdx.x & 63;
  const float* xr = X + (size_t)n * 512;
  float v[16] = {};
  #pragma unroll
  for (int it = 0; it < 8; ++it) {
    int k = lane + it * 64;
    float xv = xr[k];
    #pragma unroll
    for (int hh = 0; hh < 8; ++hh) {
      v[2 * hh]     += xv * sw[(2 * hh) * 512 + k];
      v[2 * hh + 1] += xv * sw[(2 * hh + 1) * 512 + k];
    }
  }
  #pragma unroll
  for (int off = 32; off; off >>= 1)
    #pragma unroll
    for (int i = 0; i < 16; ++i) v[i] += __shfl_xor(v[i], off);
  if (lane == 0) {
    #pragma unroll
    for (int hh = 0; hh < 8; ++hh) {
      int idx = hh * NNODE + n;
      float f1 = v[2 * hh], f2 = v[2 * hh + 1];
      fi[idx] = f1;  fj[idx] = f2;
      eiP[idx] = __expf(f1); eiN[idx] = __expf(0.2f * f1);
      ejP[idx] = __expf(f2); ejN[idx] = __expf(0.2f * f2);
    }
  }
}

// ---------------------------------------------------------------------------
// PV split-j with MFMA, A-fragments (P) built IN REGISTERS (no pT LDS):
// wave w owns i-rows [i0+w*16, +16); A-frag row = lane&15 -> per-lane row
// constants (thr, eiP, eiN) loaded once. 2 barriers/j-tile.
// grid = (NNODE/64, NCHUNK, NH)
// ---------------------------------------------------------------------------
template<int OT, int JLEN>
__global__ __launch_bounds__(256) void pv_split(
    const short* __restrict__ hT, const float* __restrict__ fi,
    const float* __restrict__ eiP, const float* __restrict__ eiN,
    const float* __restrict__ fj, const float* __restrict__ ejP,
    const float* __restrict__ ejN, const unsigned long long* __restrict__ mask,
    float* __restrict__ pnum, float* __restrict__ pl, int Fh) {
  __shared__ short hTl[OT][64][72];     // [ot][o-col][j] bf16
  __shared__ float fjL[64], ejPL[64], ejNL[64];

  const int t      = threadIdx.x;
  const int lane   = t & 63;
  const int w      = t >> 6;
  const int i0     = blockIdx.x * 64;
  const int chunk  = blockIdx.y;
  const int nchunk = gridDim.y;
  const int h      = blockIdx.z;
  const int hN     = h * NNODE;
  const short* hTs = hT + (size_t)h * Fh * NNODE;

  const int lr = lane & 15;
  const int lk = lane >> 4;
  const int arow = i0 + w * 16 + lr;        // this lane's A-row (P row)
  const float thr  = -fi[hN + arow];
  const float eiPr = eiP[hN + arow];
  const float eiNr = eiN[hN + arow];
  const unsigned long long* mrow = mask + (size_t)arow * (NNODE / 64);

  f32x4 acc[OT][4] = {};
  float lsum = 0.0f;

  const int jbase = chunk * JLEN;
  for (int jt = 0; jt < JLEN; jt += 64) {
    const int j0 = jbase + jt;
    // stage hT tiles + per-j vectors
    {
      const int o = t >> 2, seg = t & 3;
      #pragma unroll
      for (int ot = 0; ot < OT; ++ot) {
        const short* src = hTs + (size_t)(ot * 64 + o) * NNODE + j0 + seg * 16;
        float4 v0 = *(const float4*)(src);
        float4 v1 = *(const float4*)(src + 8);
        *(float4*)&hTl[ot][o][seg * 16]     = v0;
        *(float4*)&hTl[ot][o][seg * 16 + 8] = v1;
      }
    }
    if (t < 64) {
      fjL[t]  = fj[hN + j0 + t];
      ejPL[t] = ejP[hN + j0 + t];
      ejNL[t] = ejN[hN + j0 + t];
    }
    __syncthreads();  // S1: tiles ready

    const unsigned long long mw = mrow[j0 >> 6];
    #pragma unroll
    for (int kk = 0; kk < 2; ++kk) {
      const int kc = kk * 32;
      const int kb = kc + lk * 8;
      float4 fj0 = *(const float4*)&fjL[kb];
      float4 fj1 = *(const float4*)&fjL[kb + 4];
      float4 eP0 = *(const float4*)&ejPL[kb];
      float4 eP1 = *(const float4*)&ejPL[kb + 4];
      float4 eN0 = *(const float4*)&ejNL[kb];
      float4 eN1 = *(const float4*)&ejNL[kb + 4];
      const unsigned int mb = (unsigned int)(mw >> kb) & 0xFFu;
      float pv[8];
      pv[0] = (fj0.x > thr) ? eiPr * eP0.x : eiNr * eN0.x;
      pv[1] = (fj0.y > thr) ? eiPr * eP0.y : eiNr * eN0.y;
      pv[2] = (fj0.z > thr) ? eiPr * eP0.z : eiNr * eN0.z;
      pv[3] = (fj0.w > thr) ? eiPr * eP0.w : eiNr * eN0.w;
      pv[4] = (fj1.x > thr) ? eiPr * eP1.x : eiNr * eN1.x;
      pv[5] = (fj1.y > thr) ? eiPr * eP1.y : eiNr * eN1.y;
      pv[6] = (fj1.z > thr) ? eiPr * eP1.z : eiNr * eN1.z;
      pv[7] = (fj1.w > thr) ? eiPr * eP1.w : eiNr * eN1.w;
      us8 af;
      #pragma unroll
      for (int e = 0; e < 8; ++e) {
        float p = (mb & (1u << e)) ? pv[e] : 0.0f;
        lsum += p;
        af[e] = f2bf(p);
      }
      bf16x8 a = __builtin_bit_cast(bf16x8, af);
      #pragma unroll
      for (int ot = 0; ot < OT; ++ot) {
        #pragma unroll
        for (int c = 0; c < 4; ++c) {
          bf16x8 b = *(const bf16x8*)&hTl[ot][c * 16 + lr][kb];
          acc[ot][c] = __builtin_amdgcn_mfma_f32_16x16x32_bf16(a, b, acc[ot][c], 0, 0, 0);
        }
      }
    }
    __syncthreads();  // S2: reads done before next stage
  }

  // row-sum: lanes {lr, lr+16, lr+32, lr+48} hold partial sums of row arow
  lsum += __shfl_xor(lsum, 16);
  lsum += __shfl_xor(lsum, 32);
  if (lk == 0)
    pl[(size_t)(h * nchunk + chunk) * NNODE + arow] = lsum;

  // numerator: D row = w*16 + lk*4 + reg, col = ot*64 + c*16 + lr
  float* pout = pnum + ((size_t)(h * nchunk + chunk) * NNODE + i0) * (OT * 64);
  #pragma unroll
  for (int ot = 0; ot < OT; ++ot) {
    #pragma unroll
    for (int c = 0; c < 4; ++c) {
      #pragma unroll
      for (int reg = 0; reg < 4; ++reg) {
        int row = w * 16 + lk * 4 + reg;
        int col = ot * 64 + c * 16 + lr;
        pout[(size_t)row * (OT * 64) + col] = acc[ot][c][reg];
      }
    }
  }
}

// ---------------------------------------------------------------------------
// combine L1 + fused L2 logit dots (fp32 exact):
// xcat[n][col] = sum_c pnum / sum_c pl;  fi2[n] = xcat[n]·wa2[0], fj2 likewise.
// grid = NNODE, 256 thr.
// ---------------------------------------------------------------------------
__global__ __launch_bounds__(256) void combine1_fidot(
    const float* __restrict__ pnum, const float* __restrict__ pl,
    const float* __restrict__ wa2, float* __restrict__ xcat,
    float* __restrict__ fi2, float* __restrict__ fj2,
    float* __restrict__ eiP2, float* __restrict__ eiN2,
    float* __restrict__ ejP2, float* __restrict__ ejN2) {
  const int n = blockIdx.x, t = threadIdx.x;
  float d1 = 0.f, d2 = 0.f;
  #pragma unroll
  for (int rep = 0; rep < 2; ++rep) {
    int col = t + rep * 256;
    int h = col >> 6, o = col & 63;
    float s = 0.f, L = 0.f;
    #pragma unroll
    for (int c = 0; c < 2; ++c) {
      s += pnum[((size_t)(h * 2 + c) * NNODE + n) * 64 + o];
      L += pl[(size_t)(h * 2 + c) * NNODE + n];
    }
    float xv = s / L;
    xcat[(size_t)n * 512 + col] = xv;
    d1 += xv * wa2[col];
    d2 += xv * wa2[512 + col];
  }
  #pragma unroll
  for (int off = 32; off; off >>= 1) {
    d1 += __shfl_xor(d1, off);
    d2 += __shfl_xor(d2, off);
  }
  __shared__ float red[2][4];
  if ((t & 63) == 0) { red[0][t >> 6] = d1; red[1][t >> 6] = d2; }
  __syncthreads();
  if (t == 0) {
    float f1 = red[0][0] + red[0][1] + red[0][2] + red[0][3];
    float f2 = red[1][0] + red[1][1] + red[1][2] + red[1][3];
    fi2[n] = f1;  fj2[n] = f2;
    eiP2[n] = __expf(f1); eiN2[n] = __expf(0.2f * f1);
    ejP2[n] = __expf(f2); ejN2[n] = __expf(0.2f * f2);
  }
}

// ---------------------------------------------------------------------------
// combine L2 + elu + log_softmax. grid = NNODE, 128 thr.
// ---------------------------------------------------------------------------
__global__ __launch_bounds__(128) void combine2_final(
    const float* __restrict__ pnum, const float* __restrict__ pl,
    float* __restrict__ dout) {
  const int n = blockIdx.x, t = threadIdx.x;
  float s = 0.f, L = 0.f;
  #pragma unroll
  for (int c = 0; c < 8; ++c) {
    s += pnum[((size_t)c * NNODE + n) * 128 + t];
    L += pl[(size_t)c * NNODE + n];
  }
  float v = s / L;
  float e = v > 0.f ? v : (__expf(v) - 1.0f);
  float mx = e;
  #pragma unroll
  for (int off = 32; off; off >>= 1) mx = fmaxf(mx, __shfl_xor(mx, off));
  __shared__ float r2[2];
  if ((t & 63) == 0) r2[t >> 6] = mx;
  __syncthreads();
  mx = fmaxf(r2[0], r2[1]);
  float sm = __expf(e - mx);
  #pragma unroll
  for (int off = 32; off; off >>= 1) sm += __shfl_xor(sm, off);
  __shared__ float s2[2];
  if ((t & 63) == 0) s2[t >> 6] = sm;
  __syncthreads();
  float sum = s2[0] + s2[1];
  dout[(size_t)n * 128 + t] = e - mx - __logf(sum);
}

// ---------------------------------------------------------------------------
// Workspace (floats): mask 0.5M | xcat 2M | hT 1M | pnum 4.19M | pl 0.13M |
// Wt1 0.13M | Wt2 32K | wa1 8K | wa2 1K | fi/fj/exps. Peak ~34 MB.
// ---------------------------------------------------------------------------
extern "C" void kernel_launch(void* const* d_in, const int* in_sizes, int n_in,
                              void* d_out, int out_size, void* d_ws, size_t ws_size,
                              hipStream_t stream) {
  const float* x     = (const float*)d_in[0];
  const int*   adj   = (const int*)d_in[1];
  const float* W     = (const float*)d_in[2];
  const float* a     = (const float*)d_in[3];
  const float* W_out = (const float*)d_in[4];
  const float* a_out = (const float*)d_in[5];
  float* out = (float*)d_out;

  float* ws = (float*)d_ws;
  unsigned long long* mask = (unsigned long long*)ws;   // 524288 f
  float* xcat = ws + 524288;               // 2,097,152 f
  short* hT   = (short*)(xcat + 2097152);  // 2,097,152 sh (hT1 then hT2)
  float* pnum = (float*)(((short*)hT) + 2097152);  // 4,194,304 f
  float* pl   = pnum + 4194304;            // 131,072 f
  short* Wt1  = (short*)(pl + 131072);     // 262,144 sh
  short* Wt2  = Wt1 + 262144;              // 65,536 sh
  float* wa1  = (float*)(Wt2 + 65536);     // 8,192 f
  float* wa2  = wa1 + 8192;                // 1,024 f
  float* fi1  = wa2 + 1024;
  float* fj1  = fi1 + 32768;
  float* eiP1 = fj1 + 32768;
  float* eiN1 = eiP1 + 32768;
  float* ejP1 = eiN1 + 32768;
  float* ejN1 = ejP1 + 32768;
  float* fi2  = ejN1 + 32768;
  float* fj2  = fi2 + 4096;
  float* eiP2 = fj2 + 4096;
  float* eiN2 = eiP2 + 4096;
  float* ejP2 = eiN2 + 4096;
  float* ejN2 = ejP2 + 4096;

  packadj<<<dim3(NNODE * NNODE / 64 / 4), 256, 0, stream>>>(adj, mask);
  transpose_bf16<<<dim3(8, 1, 8), 256, 0, stream>>>(W, Wt1, 512, 64);
  transpose_bf16<<<dim3(8, 2, 1), 256, 0, stream>>>(W_out, Wt2, 512, 128);
  wa_kernel<64><<<dim3(8 * 512 / 4), 256, 0, stream>>>(W, a, wa1);
  wa_kernel<128><<<dim3(512 / 4), 256, 0, stream>>>(W_out, a_out, wa2);

  // ---- layer 1 ----
  gemm_mfma<<<dim3(64, 1, 8), 256, 0, stream>>>(x, Wt1, hT, 4096, 512, 64);
  fidot8<<<dim3(4096 / 4), 256, 0, stream>>>(x, wa1, fi1, fj1, eiP1, eiN1, ejP1, ejN1);
  pv_split<1, 2048><<<dim3(64, 2, 8), 256, 0, stream>>>(hT, fi1, eiP1, eiN1, fj1, ejP1, ejN1, mask, pnum, pl, 64);
  combine1_fidot<<<dim3(NNODE), 256, 0, stream>>>(pnum, pl, wa2, xcat, fi2, fj2, eiP2, eiN2, ejP2, ejN2);

  // ---- layer 2 ----
  gemm_mfma<<<dim3(64, 2, 1), 256, 0, stream>>>(xcat, Wt2, hT, 4096, 512, 128);
  pv_split<2, 512><<<dim3(64, 8, 1), 256, 0, stream>>>(hT, fi2, eiP2, eiN2, fj2, ejP2, ejN2, mask, pnum, pl, 128);
  combine2_final<<<dim3(NNODE), 128, 0, stream>>>(pnum, pl, out);
}

// Round 10
// 244.098 us; speedup vs baseline: 3.3610x; 1.0160x over previous
//
#include <hip/hip_runtime.h>
#include <hip/hip_bf16.h>

#define NNODE 4096

typedef __attribute__((ext_vector_type(8))) short bf16x8;
typedef __attribute__((ext_vector_type(4))) float f32x4;
typedef __attribute__((ext_vector_type(4))) unsigned short us4;
typedef __attribute__((ext_vector_type(8))) unsigned short us8;

__device__ __forceinline__ unsigned short f2bf(float x) {
  __hip_bfloat16 b = __float2bfloat16(x);
  return __builtin_bit_cast(unsigned short, b);
}

// ---------------------------------------------------------------------------
// adj (0/1 int32) -> bitmask, one u64 per 64 columns.
// ---------------------------------------------------------------------------
__global__ __launch_bounds__(256) void packadj(
    const int* __restrict__ adj, unsigned long long* __restrict__ mask) {
  size_t wid = (size_t)blockIdx.x * 4 + (threadIdx.x >> 6);
  int v = adj[wid * 64 + (threadIdx.x & 63)];
  unsigned long long b = __ballot(v != 0);
  if ((threadIdx.x & 63) == 0) mask[wid] = b;
}

// ---------------------------------------------------------------------------
// transpose + bf16 cast: src [h][Nr][Fsrc] f32 -> dst [h][Fsrc][Nr] bf16
// (weights only)
// ---------------------------------------------------------------------------
__global__ __launch_bounds__(256) void transpose_bf16(
    const float* __restrict__ src, short* __restrict__ dst, int Nr, int Fsrc) {
  __shared__ float tile[64][68];
  const int t  = threadIdx.x;
  const int n0 = blockIdx.x * 64, o0 = blockIdx.y * 64;
  const int h  = blockIdx.z;
  const float* S = src + ((size_t)h * Nr + n0) * Fsrc + o0;
  short* D = dst + ((size_t)h * Fsrc + o0) * Nr + n0;
  const int r = t >> 2, cs = (t & 3) * 16;
  #pragma unroll
  for (int k2 = 0; k2 < 4; ++k2) {
    float4 v = *(const float4*)&S[(size_t)r * Fsrc + cs + k2 * 4];
    *(float4*)&tile[r][cs + k2 * 4] = v;
  }
  __syncthreads();
  const int o = t >> 2, ns = (t & 3) * 16;
  us8 u0, u1;
  #pragma unroll
  for (int e = 0; e < 8; ++e) u0[e] = f2bf(tile[ns + e][o]);
  #pragma unroll
  for (int e = 0; e < 8; ++e) u1[e] = f2bf(tile[ns + 8 + e][o]);
  *(us8*)&D[(size_t)o * Nr + ns]     = u0;
  *(us8*)&D[(size_t)o * Nr + ns + 8] = u1;
}

// ---------------------------------------------------------------------------
// GEMM via MFMA, bf16 A input, fused transpose epilogue:
// hT[h][o][n] (bf16) = (A @ B[h])^T.  A MxK bf16, Wt bf16 [h][Nfull][K].
// 64x64 tile, 4 waves (2x2), 2x2 frags, BK=64, B double-buffered.
// grid = (M/64, Nfull/64, H)
// ---------------------------------------------------------------------------
__global__ __launch_bounds__(256) void gemm_mfma(
    const short* __restrict__ A, const short* __restrict__ Wt,
    short* __restrict__ hTout, int M, int K, int Nfull) {
  __shared__ short As[64][72];   // [row][k] bf16
  const int t  = threadIdx.x;
  const int lane = t & 63;
  const int w  = t >> 6;
  const int i0 = blockIdx.x * 64;
  const int c0 = blockIdx.y * 64;
  const int h  = blockIdx.z;
  const short* Bh = Wt + ((size_t)h * Nfull + c0) * K;
  short*       Hh = hTout + (size_t)h * Nfull * M;

  const int R0 = (w >> 1) * 32;
  const int C0 = (w & 1) * 32;
  const int lr = lane & 15;
  const int lk = lane >> 4;

  const int arow = t >> 2;
  const int aseg = (t & 3) * 16;

  f32x4 acc[2][2] = {};

  const short* b00p = &Bh[(size_t)(C0 + lr) * K + lk * 8];
  const short* b10p = &Bh[(size_t)(C0 + 16 + lr) * K + lk * 8];

  bf16x8 bc[4];
  bc[0] = *(const bf16x8*)(b00p);
  bc[1] = *(const bf16x8*)(b10p);
  bc[2] = *(const bf16x8*)(b00p + 32);
  bc[3] = *(const bf16x8*)(b10p + 32);

  for (int k0 = 0; k0 < K; k0 += 64) {
    {
      const short* src = &A[(size_t)(i0 + arow) * K + k0 + aseg];
      us8 u0 = *(const us8*)(src);
      us8 u1 = *(const us8*)(src + 8);
      *(us8*)&As[arow][aseg]     = u0;
      *(us8*)&As[arow][aseg + 8] = u1;
    }
    bf16x8 bn[4];
    {
      int kn = (k0 + 64 < K) ? (k0 + 64) : k0;
      bn[0] = *(const bf16x8*)(b00p + kn);
      bn[1] = *(const bf16x8*)(b10p + kn);
      bn[2] = *(const bf16x8*)(b00p + kn + 32);
      bn[3] = *(const bf16x8*)(b10p + kn + 32);
    }
    __syncthreads();
    #pragma unroll
    for (int kc = 0; kc < 64; kc += 32) {
      bf16x8 a0 = *(const bf16x8*)&As[R0 + lr][kc + lk * 8];
      bf16x8 a1 = *(const bf16x8*)&As[R0 + 16 + lr][kc + lk * 8];
      bf16x8 b0 = bc[(kc >> 5) * 2 + 0];
      bf16x8 b1 = bc[(kc >> 5) * 2 + 1];
      acc[0][0] = __builtin_amdgcn_mfma_f32_16x16x32_bf16(a0, b0, acc[0][0], 0, 0, 0);
      acc[0][1] = __builtin_amdgcn_mfma_f32_16x16x32_bf16(a0, b1, acc[0][1], 0, 0, 0);
      acc[1][0] = __builtin_amdgcn_mfma_f32_16x16x32_bf16(a1, b0, acc[1][0], 0, 0, 0);
      acc[1][1] = __builtin_amdgcn_mfma_f32_16x16x32_bf16(a1, b1, acc[1][1], 0, 0, 0);
    }
    bc[0] = bn[0]; bc[1] = bn[1]; bc[2] = bn[2]; bc[3] = bn[3];
    __syncthreads();
  }

  // epilogue: D row = lk*4+reg (n), col = lr (o); write hT[o][n] bf16 (8B st)
  #pragma unroll
  for (int fa = 0; fa < 2; ++fa) {
    #pragma unroll
    for (int fb = 0; fb < 2; ++fb) {
      int col  = c0 + C0 + fb * 16 + lr;
      int rowb = i0 + R0 + fa * 16 + lk * 4;
      us4 pk;
      #pragma unroll
      for (int reg = 0; reg < 4; ++reg) pk[reg] = f2bf(acc[fa][fb][reg]);
      *(us4*)&Hh[(size_t)col * M + rowb] = pk;
    }
  }
}

// ---------------------------------------------------------------------------
// wa[h][0][k], wa[h][1][k] = sum_o W[h][k][o]*a[h][o or F+o]  (fp32 exact)
// ---------------------------------------------------------------------------
template<int F>
__global__ __launch_bounds__(256) void wa_kernel(
    const float* __restrict__ W, const float* __restrict__ a,
    float* __restrict__ wa) {
  const int gid  = blockIdx.x * 4 + (threadIdx.x >> 6);
  const int lane = threadIdx.x & 63;
  const int h = gid >> 9;
  const int k = gid & 511;
  const float* wrow = W + ((size_t)h * 512 + k) * F;
  const float* ah = a + h * 2 * F;
  float v1 = 0.f, v2 = 0.f;
  #pragma unroll
  for (int o = lane; o < F; o += 64) {
    float wv = wrow[o];
    v1 += wv * ah[o];
    v2 += wv * ah[F + o];
  }
  #pragma unroll
  for (int off = 32; off; off >>= 1) {
    v1 += __shfl_xor(v1, off);
    v2 += __shfl_xor(v2, off);
  }
  if (lane == 0) {
    wa[((size_t)h * 2 + 0) * 512 + k] = v1;
    wa[((size_t)h * 2 + 1) * 512 + k] = v2;
  }
}

// ---------------------------------------------------------------------------
// L1 logits (all 8 heads, one pass over x) + bf16 copy of x for the GEMM.
// One wave per node. grid = 4096/4.
// ---------------------------------------------------------------------------
__global__ __launch_bounds__(256) void fidot8(
    const float* __restrict__ X, const float* __restrict__ wa,
    short* __restrict__ xbf,
    float* __restrict__ eiP, float* __restrict__ eiN,
    float* __restrict__ ejP, float* __restrict__ ejN) {
  __shared__ float sw[8192];
  for (int idx = threadIdx.x; idx < 8192; idx += 256) sw[idx] = wa[idx];
  __syncthreads();
  const int n    = blockIdx.x * 4 + (threadIdx.x >> 6);
  const int lane = threadIdx.x & 63;
  const float* xr = X + (size_t)n * 512;
  float v[16] = {};
  #pragma unroll
  for (int it = 0; it < 8; ++it) {
    int k = lane + it * 64;
    float xv = xr[k];
    xbf[(size_t)n * 512 + k] = f2bf(xv);
    #pragma unroll
    for (int hh = 0; hh < 8; ++hh) {
      v[2 * hh]     += xv * sw[(2 * hh) * 512 + k];
      v[2 * hh + 1] += xv * sw[(2 * hh + 1) * 512 + k];
    }
  }
  #pragma unroll
  for (int off = 32; off; off >>= 1)
    #pragma unroll
    for (int i = 0; i < 16; ++i) v[i] += __shfl_xor(v[i], off);
  if (lane == 0) {
    #pragma unroll
    for (int hh = 0; hh < 8; ++hh) {
      int idx = hh * NNODE + n;
      float f1 = v[2 * hh], f2 = v[2 * hh + 1];
      eiP[idx] = __expf(f1); eiN[idx] = __expf(0.2f * f1);
      ejP[idx] = __expf(f2); ejN[idx] = __expf(0.2f * f2);
    }
  }
}

// ---------------------------------------------------------------------------
// PV split-j with MFMA. p = bit ? fmax(eiP_i*ejP_j, eiN_i*ejN_j) : 0
// (exp(leaky(s)) = exp(max(s,0.2s)) = max of the factored products — exp
// monotone). Row-sums computed by an extra MFMA with a ones B-fragment.
// Wave w owns i-rows [i0+w*16,+16); A-frag built in registers.
// grid = (NNODE/64, NCHUNK, NH)
// ---------------------------------------------------------------------------
template<int OT, int JLEN>
__global__ __launch_bounds__(256) void pv_split(
    const short* __restrict__ hT,
    const float* __restrict__ eiP, const float* __restrict__ eiN,
    const float* __restrict__ ejP, const float* __restrict__ ejN,
    const unsigned long long* __restrict__ mask,
    float* __restrict__ pnum, float* __restrict__ pl, int Fh) {
  __shared__ short hTl[OT][64][72];     // [ot][o-col][j] bf16
  __shared__ float ejPL[64], ejNL[64];

  const int t      = threadIdx.x;
  const int lane   = t & 63;
  const int w      = t >> 6;
  const int i0     = blockIdx.x * 64;
  const int chunk  = blockIdx.y;
  const int nchunk = gridDim.y;
  const int h      = blockIdx.z;
  const int hN     = h * NNODE;
  const short* hTs = hT + (size_t)h * Fh * NNODE;

  const int lr = lane & 15;
  const int lk = lane >> 4;
  const int arow = i0 + w * 16 + lr;        // this lane's A-row (P row)
  const float eiPr = eiP[hN + arow];
  const float eiNr = eiN[hN + arow];
  const unsigned long long* mrow = mask + (size_t)arow * (NNODE / 64);

  us8 onesu;
  #pragma unroll
  for (int e = 0; e < 8; ++e) onesu[e] = 0x3F80;   // bf16 1.0
  const bf16x8 ones = __builtin_bit_cast(bf16x8, onesu);

  f32x4 acc[OT][4] = {};
  f32x4 accL = {};   // row-sums via mfma(a, ones)

  const int jbase = chunk * JLEN;
  for (int jt = 0; jt < JLEN; jt += 64) {
    const int j0 = jbase + jt;
    // stage hT tiles + per-j exp vectors
    {
      const int o = t >> 2, seg = t & 3;
      #pragma unroll
      for (int ot = 0; ot < OT; ++ot) {
        const short* src = hTs + (size_t)(ot * 64 + o) * NNODE + j0 + seg * 16;
        float4 v0 = *(const float4*)(src);
        float4 v1 = *(const float4*)(src + 8);
        *(float4*)&hTl[ot][o][seg * 16]     = v0;
        *(float4*)&hTl[ot][o][seg * 16 + 8] = v1;
      }
    }
    if (t < 64) {
      ejPL[t] = ejP[hN + j0 + t];
      ejNL[t] = ejN[hN + j0 + t];
    }
    __syncthreads();  // S1: tiles ready

    const unsigned long long mw = mrow[j0 >> 6];
    #pragma unroll
    for (int kk = 0; kk < 2; ++kk) {
      const int kb = kk * 32 + lk * 8;
      float4 eP0 = *(const float4*)&ejPL[kb];
      float4 eP1 = *(const float4*)&ejPL[kb + 4];
      float4 eN0 = *(const float4*)&ejNL[kb];
      float4 eN1 = *(const float4*)&ejNL[kb + 4];
      const unsigned int mb = (unsigned int)(mw >> kb) & 0xFFu;
      float pv[8];
      pv[0] = fmaxf(eiPr * eP0.x, eiNr * eN0.x);
      pv[1] = fmaxf(eiPr * eP0.y, eiNr * eN0.y);
      pv[2] = fmaxf(eiPr * eP0.z, eiNr * eN0.z);
      pv[3] = fmaxf(eiPr * eP0.w, eiNr * eN0.w);
      pv[4] = fmaxf(eiPr * eP1.x, eiNr * eN1.x);
      pv[5] = fmaxf(eiPr * eP1.y, eiNr * eN1.y);
      pv[6] = fmaxf(eiPr * eP1.z, eiNr * eN1.z);
      pv[7] = fmaxf(eiPr * eP1.w, eiNr * eN1.w);
      us8 af;
      #pragma unroll
      for (int e = 0; e < 8; ++e)
        af[e] = f2bf((mb & (1u << e)) ? pv[e] : 0.0f);
      bf16x8 a = __builtin_bit_cast(bf16x8, af);
      accL = __builtin_amdgcn_mfma_f32_16x16x32_bf16(a, ones, accL, 0, 0, 0);
      #pragma unroll
      for (int ot = 0; ot < OT; ++ot) {
        #pragma unroll
        for (int c = 0; c < 4; ++c) {
          bf16x8 b = *(const bf16x8*)&hTl[ot][c * 16 + lr][kb];
          acc[ot][c] = __builtin_amdgcn_mfma_f32_16x16x32_bf16(a, b, acc[ot][c], 0, 0, 0);
        }
      }
    }
    __syncthreads();  // S2: reads done before next stage
  }

  // pl: D row = lk*4+reg; col 0 lanes (lr==0) hold every wave row once
  if (lr == 0) {
    #pragma unroll
    for (int reg = 0; reg < 4; ++reg)
      pl[(size_t)(h * nchunk + chunk) * NNODE + i0 + w * 16 + lk * 4 + reg] = accL[reg];
  }

  // numerator: D row = w*16 + lk*4 + reg, col = ot*64 + c*16 + lr
  float* pout = pnum + ((size_t)(h * nchunk + chunk) * NNODE + i0) * (OT * 64);
  #pragma unroll
  for (int ot = 0; ot < OT; ++ot) {
    #pragma unroll
    for (int c = 0; c < 4; ++c) {
      #pragma unroll
      for (int reg = 0; reg < 4; ++reg) {
        int row = w * 16 + lk * 4 + reg;
        int col = ot * 64 + c * 16 + lr;
        pout[(size_t)row * (OT * 64) + col] = acc[ot][c][reg];
      }
    }
  }
}

// ---------------------------------------------------------------------------
// combine L1 (-> bf16 xcat) + fused L2 logit dots (fp32 exact).
// grid = NNODE, 256 thr.
// ---------------------------------------------------------------------------
__global__ __launch_bounds__(256) void combine1_fidot(
    const float* __restrict__ pnum, const float* __restrict__ pl,
    const float* __restrict__ wa2, short* __restrict__ xcatbf,
    float* __restrict__ eiP2, float* __restrict__ eiN2,
    float* __restrict__ ejP2, float* __restrict__ ejN2) {
  const int n = blockIdx.x, t = threadIdx.x;
  float d1 = 0.f, d2 = 0.f;
  #pragma unroll
  for (int rep = 0; rep < 2; ++rep) {
    int col = t + rep * 256;
    int h = col >> 6, o = col & 63;
    float s = 0.f, L = 0.f;
    #pragma unroll
    for (int c = 0; c < 2; ++c) {
      s += pnum[((size_t)(h * 2 + c) * NNODE + n) * 64 + o];
      L += pl[(size_t)(h * 2 + c) * NNODE + n];
    }
    float xv = s / L;
    xcatbf[(size_t)n * 512 + col] = f2bf(xv);
    d1 += xv * wa2[col];
    d2 += xv * wa2[512 + col];
  }
  #pragma unroll
  for (int off = 32; off; off >>= 1) {
    d1 += __shfl_xor(d1, off);
    d2 += __shfl_xor(d2, off);
  }
  __shared__ float red[2][4];
  if ((t & 63) == 0) { red[0][t >> 6] = d1; red[1][t >> 6] = d2; }
  __syncthreads();
  if (t == 0) {
    float f1 = red[0][0] + red[0][1] + red[0][2] + red[0][3];
    float f2 = red[1][0] + red[1][1] + red[1][2] + red[1][3];
    eiP2[n] = __expf(f1); eiN2[n] = __expf(0.2f * f1);
    ejP2[n] = __expf(f2); ejN2[n] = __expf(0.2f * f2);
  }
}

// ---------------------------------------------------------------------------
// combine L2 + elu + log_softmax. grid = NNODE, 128 thr.
// ---------------------------------------------------------------------------
__global__ __launch_bounds__(128) void combine2_final(
    const float* __restrict__ pnum, const float* __restrict__ pl,
    float* __restrict__ dout) {
  const int n = blockIdx.x, t = threadIdx.x;
  float s = 0.f, L = 0.f;
  #pragma unroll
  for (int c = 0; c < 8; ++c) {
    s += pnum[((size_t)c * NNODE + n) * 128 + t];
    L += pl[(size_t)c * NNODE + n];
  }
  float v = s / L;
  float e = v > 0.f ? v : (__expf(v) - 1.0f);
  float mx = e;
  #pragma unroll
  for (int off = 32; off; off >>= 1) mx = fmaxf(mx, __shfl_xor(mx, off));
  __shared__ float r2[2];
  if ((t & 63) == 0) r2[t >> 6] = mx;
  __syncthreads();
  mx = fmaxf(r2[0], r2[1]);
  float sm = __expf(e - mx);
  #pragma unroll
  for (int off = 32; off; off >>= 1) sm += __shfl_xor(sm, off);
  __shared__ float s2[2];
  if ((t & 63) == 0) s2[t >> 6] = sm;
  __syncthreads();
  float sum = s2[0] + s2[1];
  dout[(size_t)n * 128 + t] = e - mx - __logf(sum);
}

// ---------------------------------------------------------------------------
// Workspace (floats): mask .5M | xbf 1M | xcatbf 1M | hT 1M | pnum 4.19M |
// pl .13M | Wt1 .13M | Wt2 32K | wa 9K | exps .15M.  Peak ~33 MB.
// ---------------------------------------------------------------------------
extern "C" void kernel_launch(void* const* d_in, const int* in_sizes, int n_in,
                              void* d_out, int out_size, void* d_ws, size_t ws_size,
                              hipStream_t stream) {
  const float* x     = (const float*)d_in[0];
  const int*   adj   = (const int*)d_in[1];
  const float* W     = (const float*)d_in[2];
  const float* a     = (const float*)d_in[3];
  const float* W_out = (const float*)d_in[4];
  const float* a_out = (const float*)d_in[5];
  float* out = (float*)d_out;

  float* ws = (float*)d_ws;
  unsigned long long* mask = (unsigned long long*)ws;   // 524288 f
  short* xbf    = (short*)(ws + 524288);     // 2,097,152 sh
  short* xcatbf = xbf + 2097152;             // 2,097,152 sh
  short* hT     = xcatbf + 2097152;          // 2,097,152 sh
  float* pnum = (float*)(hT + 2097152);      // 4,194,304 f
  float* pl   = pnum + 4194304;              // 131,072 f
  short* Wt1  = (short*)(pl + 131072);       // 262,144 sh
  short* Wt2  = Wt1 + 262144;                // 65,536 sh
  float* wa1  = (float*)(Wt2 + 65536);       // 8,192 f
  float* wa2  = wa1 + 8192;                  // 1,024 f
  float* eiP1 = wa2 + 1024;
  float* eiN1 = eiP1 + 32768;
  float* ejP1 = eiN1 + 32768;
  float* ejN1 = ejP1 + 32768;
  float* eiP2 = ejN1 + 32768;
  float* eiN2 = eiP2 + 4096;
  float* ejP2 = eiN2 + 4096;
  float* ejN2 = ejP2 + 4096;

  packadj<<<dim3(NNODE * NNODE / 64 / 4), 256, 0, stream>>>(adj, mask);
  transpose_bf16<<<dim3(8, 1, 8), 256, 0, stream>>>(W, Wt1, 512, 64);
  transpose_bf16<<<dim3(8, 2, 1), 256, 0, stream>>>(W_out, Wt2, 512, 128);
  wa_kernel<64><<<dim3(8 * 512 / 4), 256, 0, stream>>>(W, a, wa1);
  wa_kernel<128><<<dim3(512 / 4), 256, 0, stream>>>(W_out, a_out, wa2);

  // ---- layer 1 ----
  fidot8<<<dim3(4096 / 4), 256, 0, stream>>>(x, wa1, xbf, eiP1, eiN1, ejP1, ejN1);
  gemm_mfma<<<dim3(64, 1, 8), 256, 0, stream>>>(xbf, Wt1, hT, 4096, 512, 64);
  pv_split<1, 2048><<<dim3(64, 2, 8), 256, 0, stream>>>(hT, eiP1, eiN1, ejP1, ejN1, mask, pnum, pl, 64);
  combine1_fidot<<<dim3(NNODE), 256, 0, stream>>>(pnum, pl, wa2, xcatbf, eiP2, eiN2, ejP2, ejN2);

  // ---- layer 2 ----
  gemm_mfma<<<dim3(64, 2, 1), 256, 0, stream>>>(xcatbf, Wt2, hT, 4096, 512, 128);
  pv_split<2, 512><<<dim3(64, 8, 1), 256, 0, stream>>>(hT, eiP2, eiN2, ejP2, ejN2, mask, pnum, pl, 128);
  combine2_final<<<dim3(NNODE), 128, 0, stream>>>(pnum, pl, out);
}

// Round 11
// 239.373 us; speedup vs baseline: 3.4274x; 1.0197x over previous
//
#include <hip/hip_runtime.h>
#include <hip/hip_bf16.h>

#define NNODE 4096

typedef __attribute__((ext_vector_type(8))) short bf16x8;
typedef __attribute__((ext_vector_type(4))) float f32x4;
typedef __attribute__((ext_vector_type(4))) unsigned short us4;
typedef __attribute__((ext_vector_type(8))) unsigned short us8;

__device__ __forceinline__ unsigned short f2bf(float x) {
  __hip_bfloat16 b = __float2bfloat16(x);
  return __builtin_bit_cast(unsigned short, b);
}
__device__ __forceinline__ float bf2f(unsigned short u) {
  unsigned int v = ((unsigned int)u) << 16;
  return __builtin_bit_cast(float, v);
}

// ---------------------------------------------------------------------------
// adj (0/1 int32) -> bitmask, one u64 per 64 columns.
// ---------------------------------------------------------------------------
__global__ __launch_bounds__(256) void packadj(
    const int* __restrict__ adj, unsigned long long* __restrict__ mask) {
  size_t wid = (size_t)blockIdx.x * 4 + (threadIdx.x >> 6);
  int v = adj[wid * 64 + (threadIdx.x & 63)];
  unsigned long long b = __ballot(v != 0);
  if ((threadIdx.x & 63) == 0) mask[wid] = b;
}

// ---------------------------------------------------------------------------
// transpose + bf16 cast: src [h][Nr][Fsrc] f32 -> dst [h][Fsrc][Nr] bf16
// (weights only)
// ---------------------------------------------------------------------------
__global__ __launch_bounds__(256) void transpose_bf16(
    const float* __restrict__ src, short* __restrict__ dst, int Nr, int Fsrc) {
  __shared__ float tile[64][68];
  const int t  = threadIdx.x;
  const int n0 = blockIdx.x * 64, o0 = blockIdx.y * 64;
  const int h  = blockIdx.z;
  const float* S = src + ((size_t)h * Nr + n0) * Fsrc + o0;
  short* D = dst + ((size_t)h * Fsrc + o0) * Nr + n0;
  const int r = t >> 2, cs = (t & 3) * 16;
  #pragma unroll
  for (int k2 = 0; k2 < 4; ++k2) {
    float4 v = *(const float4*)&S[(size_t)r * Fsrc + cs + k2 * 4];
    *(float4*)&tile[r][cs + k2 * 4] = v;
  }
  __syncthreads();
  const int o = t >> 2, ns = (t & 3) * 16;
  us8 u0, u1;
  #pragma unroll
  for (int e = 0; e < 8; ++e) u0[e] = f2bf(tile[ns + e][o]);
  #pragma unroll
  for (int e = 0; e < 8; ++e) u1[e] = f2bf(tile[ns + 8 + e][o]);
  *(us8*)&D[(size_t)o * Nr + ns]     = u0;
  *(us8*)&D[(size_t)o * Nr + ns + 8] = u1;
}

// ---------------------------------------------------------------------------
// GEMM via MFMA, bf16 A input, fused transpose epilogue:
// hT[h][o][n] (bf16) = (A @ B[h])^T.  A MxK bf16, Wt bf16 [h][Nfull][K].
// 64x64 tile, 4 waves (2x2), 2x2 frags, BK=64, B double-buffered.
// grid = (M/64, Nfull/64, H)
// ---------------------------------------------------------------------------
__global__ __launch_bounds__(256) void gemm_mfma(
    const short* __restrict__ A, const short* __restrict__ Wt,
    short* __restrict__ hTout, int M, int K, int Nfull) {
  __shared__ short As[64][72];   // [row][k] bf16
  const int t  = threadIdx.x;
  const int lane = t & 63;
  const int w  = t >> 6;
  const int i0 = blockIdx.x * 64;
  const int c0 = blockIdx.y * 64;
  const int h  = blockIdx.z;
  const short* Bh = Wt + ((size_t)h * Nfull + c0) * K;
  short*       Hh = hTout + (size_t)h * Nfull * M;

  const int R0 = (w >> 1) * 32;
  const int C0 = (w & 1) * 32;
  const int lr = lane & 15;
  const int lk = lane >> 4;

  const int arow = t >> 2;
  const int aseg = (t & 3) * 16;

  f32x4 acc[2][2] = {};

  const short* b00p = &Bh[(size_t)(C0 + lr) * K + lk * 8];
  const short* b10p = &Bh[(size_t)(C0 + 16 + lr) * K + lk * 8];

  bf16x8 bc[4];
  bc[0] = *(const bf16x8*)(b00p);
  bc[1] = *(const bf16x8*)(b10p);
  bc[2] = *(const bf16x8*)(b00p + 32);
  bc[3] = *(const bf16x8*)(b10p + 32);

  for (int k0 = 0; k0 < K; k0 += 64) {
    {
      const short* src = &A[(size_t)(i0 + arow) * K + k0 + aseg];
      us8 u0 = *(const us8*)(src);
      us8 u1 = *(const us8*)(src + 8);
      *(us8*)&As[arow][aseg]     = u0;
      *(us8*)&As[arow][aseg + 8] = u1;
    }
    bf16x8 bn[4];
    {
      int kn = (k0 + 64 < K) ? (k0 + 64) : k0;
      bn[0] = *(const bf16x8*)(b00p + kn);
      bn[1] = *(const bf16x8*)(b10p + kn);
      bn[2] = *(const bf16x8*)(b00p + kn + 32);
      bn[3] = *(const bf16x8*)(b10p + kn + 32);
    }
    __syncthreads();
    #pragma unroll
    for (int kc = 0; kc < 64; kc += 32) {
      bf16x8 a0 = *(const bf16x8*)&As[R0 + lr][kc + lk * 8];
      bf16x8 a1 = *(const bf16x8*)&As[R0 + 16 + lr][kc + lk * 8];
      bf16x8 b0 = bc[(kc >> 5) * 2 + 0];
      bf16x8 b1 = bc[(kc >> 5) * 2 + 1];
      acc[0][0] = __builtin_amdgcn_mfma_f32_16x16x32_bf16(a0, b0, acc[0][0], 0, 0, 0);
      acc[0][1] = __builtin_amdgcn_mfma_f32_16x16x32_bf16(a0, b1, acc[0][1], 0, 0, 0);
      acc[1][0] = __builtin_amdgcn_mfma_f32_16x16x32_bf16(a1, b0, acc[1][0], 0, 0, 0);
      acc[1][1] = __builtin_amdgcn_mfma_f32_16x16x32_bf16(a1, b1, acc[1][1], 0, 0, 0);
    }
    bc[0] = bn[0]; bc[1] = bn[1]; bc[2] = bn[2]; bc[3] = bn[3];
    __syncthreads();
  }

  // epilogue: D row = lk*4+reg (n), col = lr (o); write hT[o][n] bf16 (8B st)
  #pragma unroll
  for (int fa = 0; fa < 2; ++fa) {
    #pragma unroll
    for (int fb = 0; fb < 2; ++fb) {
      int col  = c0 + C0 + fb * 16 + lr;
      int rowb = i0 + R0 + fa * 16 + lk * 4;
      us4 pk;
      #pragma unroll
      for (int reg = 0; reg < 4; ++reg) pk[reg] = f2bf(acc[fa][fb][reg]);
      *(us4*)&Hh[(size_t)col * M + rowb] = pk;
    }
  }
}

// ---------------------------------------------------------------------------
// wa[h][0][k], wa[h][1][k] = sum_o W[h][k][o]*a[h][o or F+o]  (fp32 exact)
// ---------------------------------------------------------------------------
template<int F>
__global__ __launch_bounds__(256) void wa_kernel(
    const float* __restrict__ W, const float* __restrict__ a,
    float* __restrict__ wa) {
  const int gid  = blockIdx.x * 4 + (threadIdx.x >> 6);
  const int lane = threadIdx.x & 63;
  const int h = gid >> 9;
  const int k = gid & 511;
  const float* wrow = W + ((size_t)h * 512 + k) * F;
  const float* ah = a + h * 2 * F;
  float v1 = 0.f, v2 = 0.f;
  #pragma unroll
  for (int o = lane; o < F; o += 64) {
    float wv = wrow[o];
    v1 += wv * ah[o];
    v2 += wv * ah[F + o];
  }
  #pragma unroll
  for (int off = 32; off; off >>= 1) {
    v1 += __shfl_xor(v1, off);
    v2 += __shfl_xor(v2, off);
  }
  if (lane == 0) {
    wa[((size_t)h * 2 + 0) * 512 + k] = v1;
    wa[((size_t)h * 2 + 1) * 512 + k] = v2;
  }
}

// ---------------------------------------------------------------------------
// L1 logits (all 8 heads, one pass over x) + bf16 copy of x for the GEMM.
// One wave per node. grid = 4096/4.
// ---------------------------------------------------------------------------
__global__ __launch_bounds__(256) void fidot8(
    const float* __restrict__ X, const float* __restrict__ wa,
    short* __restrict__ xbf,
    float* __restrict__ eiP, float* __restrict__ eiN,
    float* __restrict__ ejP, float* __restrict__ ejN) {
  __shared__ float sw[8192];
  for (int idx = threadIdx.x; idx < 8192; idx += 256) sw[idx] = wa[idx];
  __syncthreads();
  const int n    = blockIdx.x * 4 + (threadIdx.x >> 6);
  const int lane = threadIdx.x & 63;
  const float* xr = X + (size_t)n * 512;
  float v[16] = {};
  #pragma unroll
  for (int it = 0; it < 8; ++it) {
    int k = lane + it * 64;
    float xv = xr[k];
    xbf[(size_t)n * 512 + k] = f2bf(xv);
    #pragma unroll
    for (int hh = 0; hh < 8; ++hh) {
      v[2 * hh]     += xv * sw[(2 * hh) * 512 + k];
      v[2 * hh + 1] += xv * sw[(2 * hh + 1) * 512 + k];
    }
  }
  #pragma unroll
  for (int off = 32; off; off >>= 1)
    #pragma unroll
    for (int i = 0; i < 16; ++i) v[i] += __shfl_xor(v[i], off);
  if (lane == 0) {
    #pragma unroll
    for (int hh = 0; hh < 8; ++hh) {
      int idx = hh * NNODE + n;
      float f1 = v[2 * hh], f2 = v[2 * hh + 1];
      eiP[idx] = __expf(f1); eiN[idx] = __expf(0.2f * f1);
      ejP[idx] = __expf(f2); ejN[idx] = __expf(0.2f * f2);
    }
  }
}

// ---------------------------------------------------------------------------
// PV split-j with MFMA. p = bit ? fmax(eiP_i*ejP_j, eiN_i*ejN_j) : 0
// Row-sums via an extra MFMA with ones B-fragment. Partial numerator stored
// bf16 (halves write traffic; fp32 combine-sum downstream).
// grid = (NNODE/64, NCHUNK, NH)
// ---------------------------------------------------------------------------
template<int OT, int JLEN>
__global__ __launch_bounds__(256) void pv_split(
    const short* __restrict__ hT,
    const float* __restrict__ eiP, const float* __restrict__ eiN,
    const float* __restrict__ ejP, const float* __restrict__ ejN,
    const unsigned long long* __restrict__ mask,
    short* __restrict__ pnum, float* __restrict__ pl, int Fh) {
  __shared__ short hTl[OT][64][72];     // [ot][o-col][j] bf16
  __shared__ float ejPL[64], ejNL[64];

  const int t      = threadIdx.x;
  const int lane   = t & 63;
  const int w      = t >> 6;
  const int i0     = blockIdx.x * 64;
  const int chunk  = blockIdx.y;
  const int nchunk = gridDim.y;
  const int h      = blockIdx.z;
  const int hN     = h * NNODE;
  const short* hTs = hT + (size_t)h * Fh * NNODE;

  const int lr = lane & 15;
  const int lk = lane >> 4;
  const int arow = i0 + w * 16 + lr;        // this lane's A-row (P row)
  const float eiPr = eiP[hN + arow];
  const float eiNr = eiN[hN + arow];
  const unsigned long long* mrow = mask + (size_t)arow * (NNODE / 64);

  us8 onesu;
  #pragma unroll
  for (int e = 0; e < 8; ++e) onesu[e] = 0x3F80;   // bf16 1.0
  const bf16x8 ones = __builtin_bit_cast(bf16x8, onesu);

  f32x4 acc[OT][4] = {};
  f32x4 accL = {};   // row-sums via mfma(a, ones)

  const int jbase = chunk * JLEN;
  for (int jt = 0; jt < JLEN; jt += 64) {
    const int j0 = jbase + jt;
    // stage hT tiles + per-j exp vectors
    {
      const int o = t >> 2, seg = t & 3;
      #pragma unroll
      for (int ot = 0; ot < OT; ++ot) {
        const short* src = hTs + (size_t)(ot * 64 + o) * NNODE + j0 + seg * 16;
        float4 v0 = *(const float4*)(src);
        float4 v1 = *(const float4*)(src + 8);
        *(float4*)&hTl[ot][o][seg * 16]     = v0;
        *(float4*)&hTl[ot][o][seg * 16 + 8] = v1;
      }
    }
    if (t < 64) {
      ejPL[t] = ejP[hN + j0 + t];
      ejNL[t] = ejN[hN + j0 + t];
    }
    __syncthreads();  // S1: tiles ready

    const unsigned long long mw = mrow[j0 >> 6];
    #pragma unroll
    for (int kk = 0; kk < 2; ++kk) {
      const int kb = kk * 32 + lk * 8;
      float4 eP0 = *(const float4*)&ejPL[kb];
      float4 eP1 = *(const float4*)&ejPL[kb + 4];
      float4 eN0 = *(const float4*)&ejNL[kb];
      float4 eN1 = *(const float4*)&ejNL[kb + 4];
      const unsigned int mb = (unsigned int)(mw >> kb) & 0xFFu;
      float pv[8];
      pv[0] = fmaxf(eiPr * eP0.x, eiNr * eN0.x);
      pv[1] = fmaxf(eiPr * eP0.y, eiNr * eN0.y);
      pv[2] = fmaxf(eiPr * eP0.z, eiNr * eN0.z);
      pv[3] = fmaxf(eiPr * eP0.w, eiNr * eN0.w);
      pv[4] = fmaxf(eiPr * eP1.x, eiNr * eN1.x);
      pv[5] = fmaxf(eiPr * eP1.y, eiNr * eN1.y);
      pv[6] = fmaxf(eiPr * eP1.z, eiNr * eN1.z);
      pv[7] = fmaxf(eiPr * eP1.w, eiNr * eN1.w);
      us8 af;
      #pragma unroll
      for (int e = 0; e < 8; ++e)
        af[e] = f2bf((mb & (1u << e)) ? pv[e] : 0.0f);
      bf16x8 a = __builtin_bit_cast(bf16x8, af);
      accL = __builtin_amdgcn_mfma_f32_16x16x32_bf16(a, ones, accL, 0, 0, 0);
      #pragma unroll
      for (int ot = 0; ot < OT; ++ot) {
        #pragma unroll
        for (int c = 0; c < 4; ++c) {
          bf16x8 b = *(const bf16x8*)&hTl[ot][c * 16 + lr][kb];
          acc[ot][c] = __builtin_amdgcn_mfma_f32_16x16x32_bf16(a, b, acc[ot][c], 0, 0, 0);
        }
      }
    }
    __syncthreads();  // S2: reads done before next stage
  }

  // pl: D row = lk*4+reg; col 0 lanes (lr==0) hold every wave row once
  if (lr == 0) {
    #pragma unroll
    for (int reg = 0; reg < 4; ++reg)
      pl[(size_t)(h * nchunk + chunk) * NNODE + i0 + w * 16 + lk * 4 + reg] = accL[reg];
  }

  // numerator (bf16): D row = w*16 + lk*4 + reg, col = ot*64 + c*16 + lr
  short* pout = pnum + ((size_t)(h * nchunk + chunk) * NNODE + i0) * (OT * 64);
  #pragma unroll
  for (int ot = 0; ot < OT; ++ot) {
    #pragma unroll
    for (int c = 0; c < 4; ++c) {
      #pragma unroll
      for (int reg = 0; reg < 4; ++reg) {
        int row = w * 16 + lk * 4 + reg;
        int col = ot * 64 + c * 16 + lr;
        pout[(size_t)row * (OT * 64) + col] = f2bf(acc[ot][c][reg]);
      }
    }
  }
}

// ---------------------------------------------------------------------------
// combine L1 (-> bf16 xcat) + fused L2 logit dots (fp32 exact). NC=4 chunks.
// grid = NNODE, 256 thr.
// ---------------------------------------------------------------------------
__global__ __launch_bounds__(256) void combine1_fidot(
    const short* __restrict__ pnum, const float* __restrict__ pl,
    const float* __restrict__ wa2, short* __restrict__ xcatbf,
    float* __restrict__ eiP2, float* __restrict__ eiN2,
    float* __restrict__ ejP2, float* __restrict__ ejN2) {
  const int n = blockIdx.x, t = threadIdx.x;
  float d1 = 0.f, d2 = 0.f;
  #pragma unroll
  for (int rep = 0; rep < 2; ++rep) {
    int col = t + rep * 256;
    int h = col >> 6, o = col & 63;
    float s = 0.f, L = 0.f;
    #pragma unroll
    for (int c = 0; c < 4; ++c) {
      s += bf2f((unsigned short)pnum[((size_t)(h * 4 + c) * NNODE + n) * 64 + o]);
      L += pl[(size_t)(h * 4 + c) * NNODE + n];
    }
    float xv = s / L;
    xcatbf[(size_t)n * 512 + col] = f2bf(xv);
    d1 += xv * wa2[col];
    d2 += xv * wa2[512 + col];
  }
  #pragma unroll
  for (int off = 32; off; off >>= 1) {
    d1 += __shfl_xor(d1, off);
    d2 += __shfl_xor(d2, off);
  }
  __shared__ float red[2][4];
  if ((t & 63) == 0) { red[0][t >> 6] = d1; red[1][t >> 6] = d2; }
  __syncthreads();
  if (t == 0) {
    float f1 = red[0][0] + red[0][1] + red[0][2] + red[0][3];
    float f2 = red[1][0] + red[1][1] + red[1][2] + red[1][3];
    eiP2[n] = __expf(f1); eiN2[n] = __expf(0.2f * f1);
    ejP2[n] = __expf(f2); ejN2[n] = __expf(0.2f * f2);
  }
}

// ---------------------------------------------------------------------------
// combine L2 (16 chunks) + elu + log_softmax. grid = NNODE, 128 thr.
// ---------------------------------------------------------------------------
__global__ __launch_bounds__(128) void combine2_final(
    const short* __restrict__ pnum, const float* __restrict__ pl,
    float* __restrict__ dout) {
  const int n = blockIdx.x, t = threadIdx.x;
  float s = 0.f, L = 0.f;
  #pragma unroll
  for (int c = 0; c < 16; ++c) {
    s += bf2f((unsigned short)pnum[((size_t)c * NNODE + n) * 128 + t]);
    L += pl[(size_t)c * NNODE + n];
  }
  float v = s / L;
  float e = v > 0.f ? v : (__expf(v) - 1.0f);
  float mx = e;
  #pragma unroll
  for (int off = 32; off; off >>= 1) mx = fmaxf(mx, __shfl_xor(mx, off));
  __shared__ float r2[2];
  if ((t & 63) == 0) r2[t >> 6] = mx;
  __syncthreads();
  mx = fmaxf(r2[0], r2[1]);
  float sm = __expf(e - mx);
  #pragma unroll
  for (int off = 32; off; off >>= 1) sm += __shfl_xor(sm, off);
  __shared__ float s2[2];
  if ((t & 63) == 0) s2[t >> 6] = sm;
  __syncthreads();
  float sum = s2[0] + s2[1];
  dout[(size_t)n * 128 + t] = e - mx - __logf(sum);
}

// ---------------------------------------------------------------------------
// Workspace (floats): mask .5M | xbf 1M | xcatbf 1M | hT 1M | pnum(bf16) 4.19M |
// pl .13M | Wt1 .13M | Wt2 32K | wa 9K | exps .15M.  Peak ~33 MB.
// ---------------------------------------------------------------------------
extern "C" void kernel_launch(void* const* d_in, const int* in_sizes, int n_in,
                              void* d_out, int out_size, void* d_ws, size_t ws_size,
                              hipStream_t stream) {
  const float* x     = (const float*)d_in[0];
  const int*   adj   = (const int*)d_in[1];
  const float* W     = (const float*)d_in[2];
  const float* a     = (const float*)d_in[3];
  const float* W_out = (const float*)d_in[4];
  const float* a_out = (const float*)d_in[5];
  float* out = (float*)d_out;

  float* ws = (float*)d_ws;
  unsigned long long* mask = (unsigned long long*)ws;   // 524288 f
  short* xbf    = (short*)(ws + 524288);     // 2,097,152 sh
  short* xcatbf = xbf + 2097152;             // 2,097,152 sh
  short* hT     = xcatbf + 2097152;          // 2,097,152 sh
  short* pnum   = hT + 2097152;              // 8,388,608 sh (bf16)
  float* pl   = (float*)(pnum + 8388608);    // 131,072 f
  short* Wt1  = (short*)(pl + 131072);       // 262,144 sh
  short* Wt2  = Wt1 + 262144;                // 65,536 sh
  float* wa1  = (float*)(Wt2 + 65536);       // 8,192 f
  float* wa2  = wa1 + 8192;                  // 1,024 f
  float* eiP1 = wa2 + 1024;
  float* eiN1 = eiP1 + 32768;
  float* ejP1 = eiN1 + 32768;
  float* ejN1 = ejP1 + 32768;
  float* eiP2 = ejN1 + 32768;
  float* eiN2 = eiP2 + 4096;
  float* ejP2 = eiN2 + 4096;
  float* ejN2 = ejP2 + 4096;

  packadj<<<dim3(NNODE * NNODE / 64 / 4), 256, 0, stream>>>(adj, mask);
  transpose_bf16<<<dim3(8, 1, 8), 256, 0, stream>>>(W, Wt1, 512, 64);
  transpose_bf16<<<dim3(8, 2, 1), 256, 0, stream>>>(W_out, Wt2, 512, 128);
  wa_kernel<64><<<dim3(8 * 512 / 4), 256, 0, stream>>>(W, a, wa1);
  wa_kernel<128><<<dim3(512 / 4), 256, 0, stream>>>(W_out, a_out, wa2);

  // ---- layer 1 ----
  fidot8<<<dim3(4096 / 4), 256, 0, stream>>>(x, wa1, xbf, eiP1, eiN1, ejP1, ejN1);
  gemm_mfma<<<dim3(64, 1, 8), 256, 0, stream>>>(xbf, Wt1, hT, 4096, 512, 64);
  pv_split<1, 1024><<<dim3(64, 4, 8), 256, 0, stream>>>(hT, eiP1, eiN1, ejP1, ejN1, mask, pnum, pl, 64);
  combine1_fidot<<<dim3(NNODE), 256, 0, stream>>>(pnum, pl, wa2, xcatbf, eiP2, eiN2, ejP2, ejN2);

  // ---- layer 2 ----
  gemm_mfma<<<dim3(64, 2, 1), 256, 0, stream>>>(xcatbf, Wt2, hT, 4096, 512, 128);
  pv_split<2, 256><<<dim3(64, 16, 1), 256, 0, stream>>>(hT, eiP2, eiN2, ejP2, ejN2, mask, pnum, pl, 128);
  combine2_final<<<dim3(NNODE), 128, 0, stream>>>(pnum, pl, out);
}